// Round 5
// baseline (276.569 us; speedup 1.0000x reference)
//
#include <hip/hip_runtime.h>
#include <hip/hip_fp16.h>

#define DIM 64
#define SLOPE 0.01f
#define NB 64    // nodes per block in node_proj
#define CPAD 16  // counter padding: 1 counter per 64B line (atomic contention)

// ---------------------------------------------------------------------------
// Kernel 1: per-node projections.
// Block = 256 threads = 4 waves, NB=64 nodes. v tile in LDS; lane k holds
// Wa/Wg row k in registers. Outputs: packed fp16 table zu (x=z_k, y=u_k)
// and per-node fp32 scalars s_l = z.a_l, s_r = z.a_r, t = v.gr, g0 = v.gl.
// ---------------------------------------------------------------------------
__global__ __launch_bounds__(256) void node_proj(
    const float* __restrict__ v, const float* __restrict__ Wa,
    const float* __restrict__ Wg, const float* __restrict__ a_l,
    const float* __restrict__ a_r, const float* __restrict__ gl,
    const float* __restrict__ gr,
    __half2* __restrict__ zu,
    float* __restrict__ s_l, float* __restrict__ s_r,
    float* __restrict__ t_gr, float* __restrict__ g0, int N)
{
    __shared__ float vt[NB * DIM];            // 16 KB
    int tid = threadIdx.x;
    int base = blockIdx.x * NB;
    int nvalid = N - base; if (nvalid > NB) nvalid = NB;

    const float4* vsrc = (const float4*)(v + (size_t)base * DIM);
    float4* vdst = (float4*)vt;
    for (int i = tid; i < NB * DIM / 4; i += 256) {
        int row = i >> 4;                     // 16 float4 per row
        float4 q = make_float4(0.f, 0.f, 0.f, 0.f);
        if (row < nvalid) q = vsrc[i];
        vdst[i] = q;
    }
    __syncthreads();

    int k = tid & 63, g = tid >> 6;
    float wa[DIM], wg[DIM];
    const float4* wap = (const float4*)(Wa + k * DIM);
    const float4* wgp = (const float4*)(Wg + k * DIM);
#pragma unroll
    for (int i = 0; i < 16; i++) {
        float4 qa = wap[i], qg = wgp[i];
        wa[4*i+0]=qa.x; wa[4*i+1]=qa.y; wa[4*i+2]=qa.z; wa[4*i+3]=qa.w;
        wg[4*i+0]=qg.x; wg[4*i+1]=qg.y; wg[4*i+2]=qg.z; wg[4*i+3]=qg.w;
    }
    float alk = a_l[k], ark = a_r[k], grk = gr[k], glk = gl[k];

    for (int j = 0; j < NB / 4; j++) {
        int nl = g * (NB / 4) + j;
        int n = base + nl;
        if (n >= N) break;
        const float4* vrow = (const float4*)(vt + nl * DIM);
        float zk = 0.f, uk = 0.f;
#pragma unroll
        for (int i4 = 0; i4 < 16; i4++) {
            float4 q = vrow[i4];              // wave-broadcast LDS read
            zk += q.x * wa[4*i4+0] + q.y * wa[4*i4+1] + q.z * wa[4*i4+2] + q.w * wa[4*i4+3];
            uk += q.x * wg[4*i4+0] + q.y * wg[4*i4+1] + q.z * wg[4*i4+2] + q.w * wg[4*i4+3];
        }
        zu[(size_t)n * DIM + k] = __floats2half2_rn(zk, uk);  // 256B coalesced
        float vk = vt[nl * DIM + k];
        float r1 = zk * alk, r2 = zk * ark, r3 = vk * grk, r4 = vk * glk;
        for (int off = 32; off; off >>= 1) {
            r1 += __shfl_down(r1, off, 64);
            r2 += __shfl_down(r2, off, 64);
            r3 += __shfl_down(r3, off, 64);
            r4 += __shfl_down(r4, off, 64);
        }
        if (k == 0) { s_l[n] = r1; s_r[n] = r2; t_gr[n] = r3; g0[n] = r4; }
    }
}

// ---------------------------------------------------------------------------
// CSR build: count -> scan -> scatter. Counters padded to 1/64B-line.
// ---------------------------------------------------------------------------
__global__ __launch_bounds__(256) void count_edges(
    const int* __restrict__ dst, int* __restrict__ cnt, int E)
{
    int i = blockIdx.x * 256 + threadIdx.x;
    int e = i * 4;
    if (e + 3 < E) {
        int4 d = *(const int4*)(dst + e);
        atomicAdd(&cnt[d.x * CPAD], 1); atomicAdd(&cnt[d.y * CPAD], 1);
        atomicAdd(&cnt[d.z * CPAD], 1); atomicAdd(&cnt[d.w * CPAD], 1);
    } else {
        for (; e < E; e++) atomicAdd(&cnt[dst[e] * CPAD], 1);
    }
}

__global__ __launch_bounds__(256) void scan_reduce(
    const int* __restrict__ cnt, int* __restrict__ bsum, int N)
{
    __shared__ int lds[256];
    int base = blockIdx.x * 1024;
    int s = 0;
    for (int i = threadIdx.x; i < 1024; i += 256) {
        int idx = base + i;
        if (idx < N) s += cnt[idx * CPAD];
    }
    lds[threadIdx.x] = s;
    __syncthreads();
    for (int off = 128; off; off >>= 1) {
        if (threadIdx.x < off) lds[threadIdx.x] += lds[threadIdx.x + off];
        __syncthreads();
    }
    if (threadIdx.x == 0) bsum[blockIdx.x] = lds[0];
}

__global__ void scan_bsum(int* __restrict__ bsum, int nb)
{
    int i = threadIdx.x;
    int x = (i < nb) ? bsum[i] : 0;
    int incl = x;
    for (int off = 1; off < 64; off <<= 1) {
        int y = __shfl_up(incl, off, 64);
        if (i >= off) incl += y;
    }
    if (i < nb) bsum[i] = incl - x;
}

// exclusive scan; writes compact offs & deg, and padded cursor copy
__global__ __launch_bounds__(256) void scan_final(
    const int* __restrict__ cnt, const int* __restrict__ bsum,
    int* __restrict__ offs, int* __restrict__ deg,
    int* __restrict__ cursor, int N)
{
    __shared__ int lds[256];
    int base = blockIdx.x * 1024;
    int t = threadIdx.x;
    int idx0 = base + t * 4;
    int v4[4], c4[4];
    int s = 0;
#pragma unroll
    for (int j = 0; j < 4; j++) {
        int idx = idx0 + j;
        int c = (idx < N) ? cnt[idx * CPAD] : 0;
        c4[j] = c;
        v4[j] = s;
        s += c;
    }
    lds[t] = s;
    __syncthreads();
    for (int off = 1; off < 256; off <<= 1) {
        int y = (t >= off) ? lds[t - off] : 0;
        __syncthreads();
        lds[t] += y;
        __syncthreads();
    }
    int excl = lds[t] - s + bsum[blockIdx.x];
#pragma unroll
    for (int j = 0; j < 4; j++) {
        int idx = idx0 + j;
        if (idx < N) {
            int o = excl + v4[j];
            offs[idx] = o;
            deg[idx] = c4[j];
            cursor[idx * CPAD] = o;
        }
    }
}

// scatter edges into CSR order. 4 edges/thread (4 independent atomic->store
// chains). Record is 4B: {src:16b | pw:fp16}. Non-temporal store streams the
// record past L2 so partial lines from different XCDs merge at memside.
__global__ __launch_bounds__(256) void scatter_edges(
    const int* __restrict__ src, const int* __restrict__ dst,
    const float* __restrict__ pre_w,
    int* __restrict__ cursor,
    unsigned int* __restrict__ sp_s, int E)
{
    int i = blockIdx.x * 256 + threadIdx.x;
    int e = i * 4;
    if (e + 3 < E) {
        int4 s4 = *(const int4*)(src + e);
        int4 d4 = *(const int4*)(dst + e);
        float4 p4 = *(const float4*)(pre_w + e);
        int p0 = atomicAdd(&cursor[d4.x * CPAD], 1);
        int p1 = atomicAdd(&cursor[d4.y * CPAD], 1);
        int p2 = atomicAdd(&cursor[d4.z * CPAD], 1);
        int p3 = atomicAdd(&cursor[d4.w * CPAD], 1);
        unsigned int r0 = ((unsigned)s4.x << 16) | __half_as_ushort(__float2half_rn(p4.x));
        unsigned int r1 = ((unsigned)s4.y << 16) | __half_as_ushort(__float2half_rn(p4.y));
        unsigned int r2 = ((unsigned)s4.z << 16) | __half_as_ushort(__float2half_rn(p4.z));
        unsigned int r3 = ((unsigned)s4.w << 16) | __half_as_ushort(__float2half_rn(p4.w));
        __builtin_nontemporal_store(r0, &sp_s[p0]);
        __builtin_nontemporal_store(r1, &sp_s[p1]);
        __builtin_nontemporal_store(r2, &sp_s[p2]);
        __builtin_nontemporal_store(r3, &sp_s[p3]);
    } else {
        for (; e < E; e++) {
            int s = src[e], d = dst[e];
            float pw = pre_w[e];
            int pos = atomicAdd(&cursor[d * CPAD], 1);
            unsigned int r = ((unsigned)s << 16) | __half_as_ushort(__float2half_rn(pw));
            __builtin_nontemporal_store(r, &sp_s[pos]);
        }
    }
}

// ---------------------------------------------------------------------------
// Per-dst softmax: recompute ea = leaky(pw*s_l[src] + s_r[n]) inline
// (s_r[n] segment-uniform, s_l gather is a 200KB L2-hot table), then
// max / exp-sum / normalize. 16-lane subgroup per node (deg avg 16).
// ---------------------------------------------------------------------------
__global__ __launch_bounds__(256) void edge_softmax(
    const int* __restrict__ offs, const int* __restrict__ deg_a,
    const unsigned int* __restrict__ sp_s,
    const float* __restrict__ s_l, const float* __restrict__ s_r,
    float* __restrict__ alpha_s, int N)
{
    int n = (blockIdx.x * 256 + threadIdx.x) >> 4;
    int lane = threadIdx.x & 15;
    if (n >= N) return;
    int deg = deg_a[n];
    if (deg == 0) return;
    int start = offs[n];
    float srn = s_r[n];
    float m = -INFINITY;
    for (int j = lane; j < deg; j += 16) {
        unsigned int rec = sp_s[start + j];
        float pw = __half2float(__ushort_as_half((unsigned short)(rec & 0xffffu)));
        float ea = fmaf(pw, s_l[rec >> 16], srn);
        ea = ea > 0.f ? ea : SLOPE * ea;      // leaky_relu
        alpha_s[start + j] = ea;              // contiguous per segment
        m = fmaxf(m, ea);
    }
#pragma unroll
    for (int mask = 8; mask; mask >>= 1) m = fmaxf(m, __shfl_xor(m, mask, 64));
    float ssum = 0.f;
    for (int j = lane; j < deg; j += 16) {
        float ex = __expf(alpha_s[start + j] - m);   // L1-hot reread
        alpha_s[start + j] = ex;
        ssum += ex;
    }
#pragma unroll
    for (int mask = 8; mask; mask >>= 1) ssum += __shfl_xor(ssum, mask, 64);
    float inv = 1.f / fmaxf(ssum, 1e-16f);
    for (int j = lane; j < deg; j += 16) alpha_s[start + j] *= inv;
}

// ---------------------------------------------------------------------------
// Aggregate: one wave per dst node, lane = feature dim. One packed 4B/lane
// gather per edge (fp16 z|u). Unrolled x8 so 8 gathers are in flight.
// Metadata (4B records) via the scalar pipe.
// ---------------------------------------------------------------------------
__global__ __launch_bounds__(256) void aggregate(
    const int* __restrict__ offs, const int* __restrict__ deg_a,
    const unsigned int* __restrict__ sp_s, const float* __restrict__ alpha_s,
    const __half2* __restrict__ zu,
    const float* __restrict__ t_gr, const float* __restrict__ g0,
    const float* __restrict__ gm,
    float* __restrict__ out, int N)
{
    int n = __builtin_amdgcn_readfirstlane((blockIdx.x * 256 + threadIdx.x) >> 6);
    int k = threadIdx.x & 63;
    if (n >= N) return;
    int deg = deg_a[n];
    size_t outIdx = (size_t)n * DIM + k;
    if (deg == 0) { out[outIdx] = 0.f; return; }
    int start = offs[n];

    float hk = 0.f, mfk = -INFINITY, msum = 0.f;
    int j = 0;
    for (; j + 8 <= deg; j += 8) {
        int p = start + j;
        unsigned int rec[8]; float al[8]; __half2 q[8]; float ts[8];
#pragma unroll
        for (int i = 0; i < 8; i++) rec[i] = sp_s[p + i];     // scalar seq
#pragma unroll
        for (int i = 0; i < 8; i++) al[i] = alpha_s[p + i];   // scalar seq
#pragma unroll
        for (int i = 0; i < 8; i++) q[i] = zu[(size_t)(rec[i] >> 16) * DIM + k];
#pragma unroll
        for (int i = 0; i < 8; i++) ts[i] = t_gr[rec[i] >> 16];  // scalar
#pragma unroll
        for (int i = 0; i < 8; i++) {
            float2 f = __half22float2(q[i]);
            float pw = __half2float(__ushort_as_half((unsigned short)(rec[i] & 0xffffu)));
            hk = fmaf(al[i], f.x, hk);
            mfk = fmaxf(mfk, pw * f.y);
            msum = fmaf(pw, ts[i], msum);
        }
    }
    for (; j + 4 <= deg; j += 4) {
        int p = start + j;
        unsigned int rec[4]; float al[4]; __half2 q[4]; float ts[4];
#pragma unroll
        for (int i = 0; i < 4; i++) rec[i] = sp_s[p + i];
#pragma unroll
        for (int i = 0; i < 4; i++) al[i] = alpha_s[p + i];
#pragma unroll
        for (int i = 0; i < 4; i++) q[i] = zu[(size_t)(rec[i] >> 16) * DIM + k];
#pragma unroll
        for (int i = 0; i < 4; i++) ts[i] = t_gr[rec[i] >> 16];
#pragma unroll
        for (int i = 0; i < 4; i++) {
            float2 f = __half22float2(q[i]);
            float pw = __half2float(__ushort_as_half((unsigned short)(rec[i] & 0xffffu)));
            hk = fmaf(al[i], f.x, hk);
            mfk = fmaxf(mfk, pw * f.y);
            msum = fmaf(pw, ts[i], msum);
        }
    }
    for (; j < deg; j++) {
        int p = start + j;
        unsigned int rec = sp_s[p];
        float al = alpha_s[p];
        __half2 q = zu[(size_t)(rec >> 16) * DIM + k];
        float pw = __half2float(__ushort_as_half((unsigned short)(rec & 0xffffu)));
        float2 f = __half22float2(q);
        hk = fmaf(al, f.x, hk);
        mfk = fmaxf(mfk, pw * f.y);
        msum = fmaf(pw, t_gr[rec >> 16], msum);
    }
    // wave reduction: maxFeat . gm
    float r = gm[k] * mfk;
    for (int off = 32; off; off >>= 1) r += __shfl_down(r, off, 64);
    r = __shfl(r, 0, 64);
    float meanDot = msum / (float)deg;
    float x = g0[n] + r + meanDot;
    float gate = 1.f / (1.f + __expf(-x));
    out[outIdx] = gate * hk;
}

// ---------------------------------------------------------------------------
extern "C" void kernel_launch(void* const* d_in, const int* in_sizes, int n_in,
                              void* d_out, int out_size, void* d_ws, size_t ws_size,
                              hipStream_t stream)
{
    const float* v     = (const float*)d_in[0];
    const float* pre_w = (const float*)d_in[1];
    const int*   src   = (const int*)d_in[2];
    const int*   dst   = (const int*)d_in[3];
    const float* Wa    = (const float*)d_in[4];
    const float* a_l   = (const float*)d_in[5];
    const float* a_r   = (const float*)d_in[6];
    const float* Wg    = (const float*)d_in[7];
    const float* gl    = (const float*)d_in[8];
    const float* gm    = (const float*)d_in[9];
    const float* gr    = (const float*)d_in[10];
    int N = in_sizes[0] / DIM;
    int E = in_sizes[2];

    // workspace layout (~27 MB)
    char* ws   = (char*)d_ws;
    __half2* zu = (__half2*)ws;                       // N*DIM*4B = 12.8MB
    float* s_l  = (float*)(ws + (size_t)N * DIM * 4);
    float* s_r  = s_l + N;
    float* t_gr = s_r + N;
    float* g0   = t_gr + N;
    int* offs   = (int*)(g0 + N);
    int* deg    = offs + N;
    int* bsum   = deg + N;
    int nb = (N + 1023) / 1024;
    int* cnt    = bsum + ((nb + 63) / 64) * 64;       // padded: N*CPAD ints
    int* cursor = cnt + (size_t)N * CPAD;             // padded: N*CPAD ints
    unsigned int* sp_s = (unsigned int*)(cursor + (size_t)N * CPAD);
    float* alpha_s = (float*)(sp_s + E);

    hipMemsetAsync(cnt, 0, (size_t)N * CPAD * sizeof(int), stream);

    node_proj<<<(N + NB - 1) / NB, 256, 0, stream>>>(
        v, Wa, Wg, a_l, a_r, gl, gr, zu, s_l, s_r, t_gr, g0, N);

    count_edges<<<(E / 4 + 255) / 256, 256, 0, stream>>>(dst, cnt, E);
    scan_reduce<<<nb, 256, 0, stream>>>(cnt, bsum, N);
    scan_bsum<<<1, 64, 0, stream>>>(bsum, nb);
    scan_final<<<nb, 256, 0, stream>>>(cnt, bsum, offs, deg, cursor, N);

    scatter_edges<<<(E / 4 + 255) / 256, 256, 0, stream>>>(
        src, dst, pre_w, cursor, sp_s, E);

    edge_softmax<<<(N * 16 + 255) / 256, 256, 0, stream>>>(
        offs, deg, sp_s, s_l, s_r, alpha_s, N);

    aggregate<<<(N + 3) / 4, 256, 0, stream>>>(
        offs, deg, sp_s, alpha_s, zu, t_gr, g0, gm, (float*)d_out, N);
}

// Round 6
// 231.997 us; speedup vs baseline: 1.1921x; 1.1921x over previous
//
#include <hip/hip_runtime.h>
#include <hip/hip_fp16.h>

#define DIM 64
#define SLOPE 0.01f
#define NB 64        // nodes per block in node_proj
#define P1_CHUNK 4096

// ---------------------------------------------------------------------------
// Kernel 1: per-node projections (unchanged from round 4).
// Outputs packed fp16 table zu (x=z_k, y=u_k) + fp32 scalars s_l,s_r,t,g0.
// ---------------------------------------------------------------------------
__global__ __launch_bounds__(256) void node_proj(
    const float* __restrict__ v, const float* __restrict__ Wa,
    const float* __restrict__ Wg, const float* __restrict__ a_l,
    const float* __restrict__ a_r, const float* __restrict__ gl,
    const float* __restrict__ gr,
    __half2* __restrict__ zu,
    float* __restrict__ s_l, float* __restrict__ s_r,
    float* __restrict__ t_gr, float* __restrict__ g0, int N)
{
    __shared__ float vt[NB * DIM];            // 16 KB
    int tid = threadIdx.x;
    int base = blockIdx.x * NB;
    int nvalid = N - base; if (nvalid > NB) nvalid = NB;

    const float4* vsrc = (const float4*)(v + (size_t)base * DIM);
    float4* vdst = (float4*)vt;
    for (int i = tid; i < NB * DIM / 4; i += 256) {
        int row = i >> 4;
        float4 q = make_float4(0.f, 0.f, 0.f, 0.f);
        if (row < nvalid) q = vsrc[i];
        vdst[i] = q;
    }
    __syncthreads();

    int k = tid & 63, g = tid >> 6;
    float wa[DIM], wg[DIM];
    const float4* wap = (const float4*)(Wa + k * DIM);
    const float4* wgp = (const float4*)(Wg + k * DIM);
#pragma unroll
    for (int i = 0; i < 16; i++) {
        float4 qa = wap[i], qg = wgp[i];
        wa[4*i+0]=qa.x; wa[4*i+1]=qa.y; wa[4*i+2]=qa.z; wa[4*i+3]=qa.w;
        wg[4*i+0]=qg.x; wg[4*i+1]=qg.y; wg[4*i+2]=qg.z; wg[4*i+3]=qg.w;
    }
    float alk = a_l[k], ark = a_r[k], grk = gr[k], glk = gl[k];

    for (int j = 0; j < NB / 4; j++) {
        int nl = g * (NB / 4) + j;
        int n = base + nl;
        if (n >= N) break;
        const float4* vrow = (const float4*)(vt + nl * DIM);
        float zk = 0.f, uk = 0.f;
#pragma unroll
        for (int i4 = 0; i4 < 16; i4++) {
            float4 q = vrow[i4];
            zk += q.x * wa[4*i4+0] + q.y * wa[4*i4+1] + q.z * wa[4*i4+2] + q.w * wa[4*i4+3];
            uk += q.x * wg[4*i4+0] + q.y * wg[4*i4+1] + q.z * wg[4*i4+2] + q.w * wg[4*i4+3];
        }
        zu[(size_t)n * DIM + k] = __floats2half2_rn(zk, uk);
        float vk = vt[nl * DIM + k];
        float r1 = zk * alk, r2 = zk * ark, r3 = vk * grk, r4 = vk * glk;
        for (int off = 32; off; off >>= 1) {
            r1 += __shfl_down(r1, off, 64);
            r2 += __shfl_down(r2, off, 64);
            r3 += __shfl_down(r3, off, 64);
            r4 += __shfl_down(r4, off, 64);
        }
        if (k == 0) { s_l[n] = r1; s_r[n] = r2; t_gr[n] = r3; g0[n] = r4; }
    }
}

// ---------------------------------------------------------------------------
// Bucketed CSR build: bucket = dst>>8 (196 buckets, ~4096 edges each).
// Replaces count/scan/scatter global-atomic pipeline: only 50K uncontended
// LDS-aggregated global atomics total.
// ---------------------------------------------------------------------------

// Phase 0: global bucket histogram via per-block LDS histogram.
__global__ __launch_bounds__(256) void bucket_hist(
    const int* __restrict__ dst, int* __restrict__ ghist, int E)
{
    __shared__ int h[256];
    h[threadIdx.x] = 0;
    __syncthreads();
    int stride = gridDim.x * 256;
    for (int e = blockIdx.x * 256 + threadIdx.x; e < E; e += stride)
        atomicAdd(&h[dst[e] >> 8], 1);        // LDS atomic
    __syncthreads();
    int hv = h[threadIdx.x];
    if (hv) atomicAdd(&ghist[threadIdx.x], hv);
}

// Phase 0.5: exclusive scan of 256 bucket sizes -> bbase[257] + cursor copy.
__global__ void bucket_scan(const int* __restrict__ ghist,
                            int* __restrict__ bbase, int* __restrict__ bcur)
{
    __shared__ int lds[256];
    int t = threadIdx.x;
    int x = ghist[t];
    lds[t] = x;
    __syncthreads();
    for (int off = 1; off < 256; off <<= 1) {
        int y = (t >= off) ? lds[t - off] : 0;
        __syncthreads();
        lds[t] += y;
        __syncthreads();
    }
    int excl = lds[t] - x;
    bbase[t] = excl;
    bcur[t] = excl;
    if (t == 255) bbase[256] = excl + x;
}

// Phase 1: scatter edges into their bucket region. One reservation atomic
// per (block,bucket); records land in ~128B runs (vs 4B/line before).
// Record: {lo = src<<16 | pw_fp16, hi = dst}.
__global__ __launch_bounds__(256) void bucket_scatter(
    const int* __restrict__ src, const int* __restrict__ dst,
    const float* __restrict__ pre_w,
    int* __restrict__ bcur, uint2* __restrict__ tmp, int E)
{
    __shared__ int h[256], base[256], lcur[256];
    int t = threadIdx.x;
    h[t] = 0; lcur[t] = 0;
    __syncthreads();
    int e0 = blockIdx.x * P1_CHUNK;
    int e1 = e0 + P1_CHUNK; if (e1 > E) e1 = E;
    for (int e = e0 + t; e < e1; e += 256)
        atomicAdd(&h[dst[e] >> 8], 1);        // LDS atomic
    __syncthreads();
    int hv = h[t];
    if (hv) base[t] = atomicAdd(&bcur[t], hv);  // one global atomic/bucket
    __syncthreads();
    for (int e = e0 + t; e < e1; e += 256) {
        int d = dst[e];                        // L1-hot reread
        int b = d >> 8;
        int pos = base[b] + atomicAdd(&lcur[b], 1);
        unsigned lo = ((unsigned)src[e] << 16) |
                      __half_as_ushort(__float2half_rn(pre_w[e]));
        uint2 r; r.x = lo; r.y = (unsigned)d;
        tmp[pos] = r;
    }
}

// Phase 2: one block per bucket. LDS hist of dst&255 -> per-node offs/deg
// (replaces the 3 scan kernels), placement into the block-owned ~16KB CSR
// window (single-XCD line ownership), then FUSED per-node softmax:
// thread t owns node t's segment; ea = leaky(pw*s_l[src]+s_r[n]) recomputed
// (s_l 200KB table L2-hot; records just written -> cache-hot).
__global__ __launch_bounds__(256) void bucket_to_csr(
    const uint2* __restrict__ tmp, const int* __restrict__ bbase,
    const float* __restrict__ s_l, const float* __restrict__ s_r,
    int* __restrict__ offs, int* __restrict__ deg,
    unsigned int* __restrict__ sp_s, float* __restrict__ alpha_s, int N)
{
    __shared__ int h[256], excl[256], cur[256];
    int b = blockIdx.x;
    int t = threadIdx.x;
    int start = bbase[b], end = bbase[b + 1];
    h[t] = 0; cur[t] = 0;
    __syncthreads();
    for (int i = start + t; i < end; i += 256)
        atomicAdd(&h[tmp[i].y & 255], 1);     // LDS atomic
    __syncthreads();
    int x = h[t];
    excl[t] = x;
    __syncthreads();
    for (int off = 1; off < 256; off <<= 1) {
        int y = (t >= off) ? excl[t - off] : 0;
        __syncthreads();
        excl[t] += y;
        __syncthreads();
    }
    int ex = excl[t] - x;                     // exclusive within bucket
    int n = (b << 8) + t;
    if (n < N) { offs[n] = start + ex; deg[n] = x; }
    __syncthreads();
    excl[t] = ex;
    __syncthreads();
    // placement
    for (int i = start + t; i < end; i += 256) {
        uint2 r = tmp[i];
        int d8 = r.y & 255;
        int pos = start + excl[d8] + atomicAdd(&cur[d8], 1);
        sp_s[pos] = r.x;
    }
    __syncthreads();                          // all records placed+visible
    // fused per-node softmax (serial over deg ~16, parallel over 256 nodes)
    if (n < N && x > 0) {
        int s0 = start + ex;
        float srn = s_r[n];
        float m = -INFINITY;
        for (int j = 0; j < x; j++) {
            unsigned rec = sp_s[s0 + j];
            float pw = __half2float(__ushort_as_half((unsigned short)(rec & 0xffffu)));
            float ea = fmaf(pw, s_l[rec >> 16], srn);
            ea = ea > 0.f ? ea : SLOPE * ea;  // leaky_relu
            alpha_s[s0 + j] = ea;
            m = fmaxf(m, ea);
        }
        float ssum = 0.f;
        for (int j = 0; j < x; j++) {
            float exv = __expf(alpha_s[s0 + j] - m);
            alpha_s[s0 + j] = exv;
            ssum += exv;
        }
        float inv = 1.f / fmaxf(ssum, 1e-16f);
        for (int j = 0; j < x; j++) alpha_s[s0 + j] *= inv;
    }
}

// ---------------------------------------------------------------------------
// Aggregate: one wave per dst node, lane = feature dim (unchanged).
// ---------------------------------------------------------------------------
__global__ __launch_bounds__(256) void aggregate(
    const int* __restrict__ offs, const int* __restrict__ deg_a,
    const unsigned int* __restrict__ sp_s, const float* __restrict__ alpha_s,
    const __half2* __restrict__ zu,
    const float* __restrict__ t_gr, const float* __restrict__ g0,
    const float* __restrict__ gm,
    float* __restrict__ out, int N)
{
    int n = __builtin_amdgcn_readfirstlane((blockIdx.x * 256 + threadIdx.x) >> 6);
    int k = threadIdx.x & 63;
    if (n >= N) return;
    int deg = deg_a[n];
    size_t outIdx = (size_t)n * DIM + k;
    if (deg == 0) { out[outIdx] = 0.f; return; }
    int start = offs[n];

    float hk = 0.f, mfk = -INFINITY, msum = 0.f;
    int j = 0;
    for (; j + 8 <= deg; j += 8) {
        int p = start + j;
        unsigned int rec[8]; float al[8]; __half2 q[8]; float ts[8];
#pragma unroll
        for (int i = 0; i < 8; i++) rec[i] = sp_s[p + i];
#pragma unroll
        for (int i = 0; i < 8; i++) al[i] = alpha_s[p + i];
#pragma unroll
        for (int i = 0; i < 8; i++) q[i] = zu[(size_t)(rec[i] >> 16) * DIM + k];
#pragma unroll
        for (int i = 0; i < 8; i++) ts[i] = t_gr[rec[i] >> 16];
#pragma unroll
        for (int i = 0; i < 8; i++) {
            float2 f = __half22float2(q[i]);
            float pw = __half2float(__ushort_as_half((unsigned short)(rec[i] & 0xffffu)));
            hk = fmaf(al[i], f.x, hk);
            mfk = fmaxf(mfk, pw * f.y);
            msum = fmaf(pw, ts[i], msum);
        }
    }
    for (; j + 4 <= deg; j += 4) {
        int p = start + j;
        unsigned int rec[4]; float al[4]; __half2 q[4]; float ts[4];
#pragma unroll
        for (int i = 0; i < 4; i++) rec[i] = sp_s[p + i];
#pragma unroll
        for (int i = 0; i < 4; i++) al[i] = alpha_s[p + i];
#pragma unroll
        for (int i = 0; i < 4; i++) q[i] = zu[(size_t)(rec[i] >> 16) * DIM + k];
#pragma unroll
        for (int i = 0; i < 4; i++) ts[i] = t_gr[rec[i] >> 16];
#pragma unroll
        for (int i = 0; i < 4; i++) {
            float2 f = __half22float2(q[i]);
            float pw = __half2float(__ushort_as_half((unsigned short)(rec[i] & 0xffffu)));
            hk = fmaf(al[i], f.x, hk);
            mfk = fmaxf(mfk, pw * f.y);
            msum = fmaf(pw, ts[i], msum);
        }
    }
    for (; j < deg; j++) {
        int p = start + j;
        unsigned int rec = sp_s[p];
        float al = alpha_s[p];
        __half2 q = zu[(size_t)(rec >> 16) * DIM + k];
        float pw = __half2float(__ushort_as_half((unsigned short)(rec & 0xffffu)));
        float2 f = __half22float2(q);
        hk = fmaf(al, f.x, hk);
        mfk = fmaxf(mfk, pw * f.y);
        msum = fmaf(pw, t_gr[rec >> 16], msum);
    }
    float r = gm[k] * mfk;
    for (int off = 32; off; off >>= 1) r += __shfl_down(r, off, 64);
    r = __shfl(r, 0, 64);
    float meanDot = msum / (float)deg;
    float xg = g0[n] + r + meanDot;
    float gate = 1.f / (1.f + __expf(-xg));
    out[outIdx] = gate * hk;
}

// ---------------------------------------------------------------------------
extern "C" void kernel_launch(void* const* d_in, const int* in_sizes, int n_in,
                              void* d_out, int out_size, void* d_ws, size_t ws_size,
                              hipStream_t stream)
{
    const float* v     = (const float*)d_in[0];
    const float* pre_w = (const float*)d_in[1];
    const int*   src   = (const int*)d_in[2];
    const int*   dst   = (const int*)d_in[3];
    const float* Wa    = (const float*)d_in[4];
    const float* a_l   = (const float*)d_in[5];
    const float* a_r   = (const float*)d_in[6];
    const float* Wg    = (const float*)d_in[7];
    const float* gl    = (const float*)d_in[8];
    const float* gm    = (const float*)d_in[9];
    const float* gr    = (const float*)d_in[10];
    int N = in_sizes[0] / DIM;
    int E = in_sizes[2];
    int nbuck = (N + 255) >> 8;

    // workspace layout (~27 MB)
    char* ws    = (char*)d_ws;
    __half2* zu = (__half2*)ws;                       // N*DIM*4B = 12.8MB
    float* s_l  = (float*)(ws + (size_t)N * DIM * 4);
    float* s_r  = s_l + N;
    float* t_gr = s_r + N;
    float* g0   = t_gr + N;
    int* offs   = (int*)(g0 + N);
    int* deg    = offs + N;
    int* ghist  = deg + N;                            // 256
    int* bbase  = ghist + 256;                        // 257
    int* bcur   = bbase + 260;                        // 256
    uint2* tmp  = (uint2*)(bcur + 260);               // E*8B = 6.4MB
    unsigned int* sp_s = (unsigned int*)(tmp + E);    // E*4B
    float* alpha_s = (float*)(sp_s + E);              // E*4B

    hipMemsetAsync(ghist, 0, 256 * sizeof(int), stream);

    node_proj<<<(N + NB - 1) / NB, 256, 0, stream>>>(
        v, Wa, Wg, a_l, a_r, gl, gr, zu, s_l, s_r, t_gr, g0, N);

    bucket_hist<<<(E + 2047) / 2048, 256, 0, stream>>>(dst, ghist, E);
    bucket_scan<<<1, 256, 0, stream>>>(ghist, bbase, bcur);
    bucket_scatter<<<(E + P1_CHUNK - 1) / P1_CHUNK, 256, 0, stream>>>(
        src, dst, pre_w, bcur, tmp, E);
    bucket_to_csr<<<nbuck, 256, 0, stream>>>(
        tmp, bbase, s_l, s_r, offs, deg, sp_s, alpha_s, N);

    aggregate<<<(N + 3) / 4, 256, 0, stream>>>(
        offs, deg, sp_s, alpha_s, zu, t_gr, g0, gm, (float*)d_out, N);
}

// Round 7
// 197.959 us; speedup vs baseline: 1.3971x; 1.1719x over previous
//
#include <hip/hip_runtime.h>
#include <hip/hip_fp16.h>

#define DIM 64
#define SLOPE 0.01f
#define P1_CHUNK 4096
#define LDH 72   // LDS row stride in halves (64 + 8 pad -> breaks 128B-stride bank aliasing)

typedef _Float16 half8 __attribute__((ext_vector_type(8)));
typedef float float4v __attribute__((ext_vector_type(4)));

// ---------------------------------------------------------------------------
// Kernel 1: per-node projections via MFMA (f32_16x16x32_f16).
// Block = 256 threads = 4 waves, 64 nodes. v/Wa/Wg staged fp16 in LDS
// (padded rows). Wave w computes node strip [w*16, w*16+16):
//   z (4 col-tiles x 2 MFMA) + u (8 MFMA) + scalars (2 MFMA vs 4-col B:
//   [gl; gr; Wa^T a_l; Wa^T a_r]  -- s_l = z.a_l = v.(Wa^T a_l)).
// Layouts (HW-verified, cdna docs): A[m=lane&15][k=quad*8+j],
// B[k=quad*8+j][n=lane&15], C col=lane&15, row=quad*4+reg.
// ---------------------------------------------------------------------------
__global__ __launch_bounds__(256) void node_proj(
    const float* __restrict__ v, const float* __restrict__ Wa,
    const float* __restrict__ Wg, const float* __restrict__ a_l,
    const float* __restrict__ a_r, const float* __restrict__ gl,
    const float* __restrict__ gr,
    __half2* __restrict__ zu,
    float* __restrict__ s_l, float* __restrict__ s_r,
    float* __restrict__ t_gr, float* __restrict__ g0, int N)
{
    __shared__ _Float16 vt[64 * LDH];    // 9.2 KB
    __shared__ _Float16 wah[64 * LDH];
    __shared__ _Float16 wgh[64 * LDH];
    __shared__ _Float16 bx[16 * LDH];    // rows: 0=gl 1=gr 2=Wa^T a_l 3=Wa^T a_r, 4..15 zero
    int tid = threadIdx.x;
    int base = blockIdx.x * 64;

    // ---- stage: fp32 -> fp16. thread t: row = t>>2, cols [(t&3)*16, +16) ----
    {
        int r = tid >> 2, i0 = (tid & 3) * 16;
        int n = base + r;
        _Float16* dv = &vt[r * LDH + i0];
        if (n < N) {
            const float4* sv = (const float4*)(v + (size_t)n * DIM + i0);
#pragma unroll
            for (int c = 0; c < 4; c++) {
                float4 q = sv[c];
                dv[4*c+0] = (_Float16)q.x; dv[4*c+1] = (_Float16)q.y;
                dv[4*c+2] = (_Float16)q.z; dv[4*c+3] = (_Float16)q.w;
            }
        } else {
#pragma unroll
            for (int c = 0; c < 16; c++) dv[c] = (_Float16)0.f;
        }
        const float4* sa = (const float4*)(Wa + (size_t)r * DIM + i0);
        const float4* sg = (const float4*)(Wg + (size_t)r * DIM + i0);
        _Float16* da = &wah[r * LDH + i0];
        _Float16* dg = &wgh[r * LDH + i0];
#pragma unroll
        for (int c = 0; c < 4; c++) {
            float4 qa = sa[c], qg = sg[c];
            da[4*c+0] = (_Float16)qa.x; da[4*c+1] = (_Float16)qa.y;
            da[4*c+2] = (_Float16)qa.z; da[4*c+3] = (_Float16)qa.w;
            dg[4*c+0] = (_Float16)qg.x; dg[4*c+1] = (_Float16)qg.y;
            dg[4*c+2] = (_Float16)qg.z; dg[4*c+3] = (_Float16)qg.w;
        }
        // bx rows 0,1 + zero rows 4..15
        if (tid < 64)       bx[0 * LDH + tid] = (_Float16)gl[tid];
        else if (tid < 128) bx[1 * LDH + (tid - 64)] = (_Float16)gr[tid - 64];
        for (int x = tid; x < 12 * 64; x += 256)
            bx[(4 + (x >> 6)) * LDH + (x & 63)] = (_Float16)0.f;
    }
    __syncthreads();
    // ---- bx rows 2,3: wa_l[i] = sum_k a_l[k]*Wa[k][i] (from fp16 LDS copy) ----
    if (tid < 64) {
        int i = tid;
        float acc = 0.f;
        for (int k = 0; k < 64; k++) acc = fmaf(a_l[k], (float)wah[k * LDH + i], acc);
        bx[2 * LDH + i] = (_Float16)acc;
    } else if (tid < 128) {
        int i = tid - 64;
        float acc = 0.f;
        for (int k = 0; k < 64; k++) acc = fmaf(a_r[k], (float)wah[k * LDH + i], acc);
        bx[3 * LDH + i] = (_Float16)acc;
    }
    __syncthreads();

    // ---- MFMA phase ----
    int lane = tid & 63;
    int m0 = (tid >> 6) * 16;            // wave's node strip
    int rb = lane & 15;                  // A row / B col within tile
    int q  = lane >> 4;                  // quad

    half8 a_lo = *(const half8*)&vt[(m0 + rb) * LDH + q * 8];
    half8 a_hi = *(const half8*)&vt[(m0 + rb) * LDH + 32 + q * 8];

    float4v zacc[4], uacc[4], sacc;
#pragma unroll
    for (int tc = 0; tc < 4; tc++) { zacc[tc] = (float4v)0.f; uacc[tc] = (float4v)0.f; }
    sacc = (float4v)0.f;

#pragma unroll
    for (int tc = 0; tc < 4; tc++) {
        int c0 = tc * 16;
        half8 blo = *(const half8*)&wah[(c0 + rb) * LDH + q * 8];
        half8 bhi = *(const half8*)&wah[(c0 + rb) * LDH + 32 + q * 8];
        zacc[tc] = __builtin_amdgcn_mfma_f32_16x16x32_f16(a_lo, blo, zacc[tc], 0, 0, 0);
        zacc[tc] = __builtin_amdgcn_mfma_f32_16x16x32_f16(a_hi, bhi, zacc[tc], 0, 0, 0);
        half8 glo = *(const half8*)&wgh[(c0 + rb) * LDH + q * 8];
        half8 ghi = *(const half8*)&wgh[(c0 + rb) * LDH + 32 + q * 8];
        uacc[tc] = __builtin_amdgcn_mfma_f32_16x16x32_f16(a_lo, glo, uacc[tc], 0, 0, 0);
        uacc[tc] = __builtin_amdgcn_mfma_f32_16x16x32_f16(a_hi, ghi, uacc[tc], 0, 0, 0);
    }
    {
        half8 blo = *(const half8*)&bx[rb * LDH + q * 8];
        half8 bhi = *(const half8*)&bx[rb * LDH + 32 + q * 8];
        sacc = __builtin_amdgcn_mfma_f32_16x16x32_f16(a_lo, blo, sacc, 0, 0, 0);
        sacc = __builtin_amdgcn_mfma_f32_16x16x32_f16(a_hi, bhi, sacc, 0, 0, 0);
    }

    // ---- epilogue: zu table (half2 pack), rows n = base+m0+q*4+r, col tc*16+rb ----
#pragma unroll
    for (int r = 0; r < 4; r++) {
        int n = base + m0 + q * 4 + r;
        if (n < N) {
#pragma unroll
            for (int tc = 0; tc < 4; tc++)
                zu[(size_t)n * DIM + tc * 16 + rb] = __floats2half2_rn(zacc[tc][r], uacc[tc][r]);
        }
    }
    // scalars: col rb of sacc holds {g0, t_gr, s_l, s_r} for rb = 0..3
    if (rb < 4) {
        float* arr = (rb == 0) ? g0 : (rb == 1) ? t_gr : (rb == 2) ? s_l : s_r;
#pragma unroll
        for (int r = 0; r < 4; r++) {
            int n = base + m0 + q * 4 + r;
            if (n < N) arr[n] = sacc[r];
        }
    }
}

// ---------------------------------------------------------------------------
// Bucketed CSR build (unchanged from round 6): bucket = dst>>8.
// ---------------------------------------------------------------------------
__global__ __launch_bounds__(256) void bucket_hist(
    const int* __restrict__ dst, int* __restrict__ ghist, int E)
{
    __shared__ int h[256];
    h[threadIdx.x] = 0;
    __syncthreads();
    int stride = gridDim.x * 256;
    for (int e = blockIdx.x * 256 + threadIdx.x; e < E; e += stride)
        atomicAdd(&h[dst[e] >> 8], 1);
    __syncthreads();
    int hv = h[threadIdx.x];
    if (hv) atomicAdd(&ghist[threadIdx.x], hv);
}

__global__ void bucket_scan(const int* __restrict__ ghist,
                            int* __restrict__ bbase, int* __restrict__ bcur)
{
    __shared__ int lds[256];
    int t = threadIdx.x;
    int x = ghist[t];
    lds[t] = x;
    __syncthreads();
    for (int off = 1; off < 256; off <<= 1) {
        int y = (t >= off) ? lds[t - off] : 0;
        __syncthreads();
        lds[t] += y;
        __syncthreads();
    }
    int excl = lds[t] - x;
    bbase[t] = excl;
    bcur[t] = excl;
    if (t == 255) bbase[256] = excl + x;
}

__global__ __launch_bounds__(256) void bucket_scatter(
    const int* __restrict__ src, const int* __restrict__ dst,
    const float* __restrict__ pre_w,
    int* __restrict__ bcur, uint2* __restrict__ tmp, int E)
{
    __shared__ int h[256], base[256], lcur[256];
    int t = threadIdx.x;
    h[t] = 0; lcur[t] = 0;
    __syncthreads();
    int e0 = blockIdx.x * P1_CHUNK;
    int e1 = e0 + P1_CHUNK; if (e1 > E) e1 = E;
    for (int e = e0 + t; e < e1; e += 256)
        atomicAdd(&h[dst[e] >> 8], 1);
    __syncthreads();
    int hv = h[t];
    if (hv) base[t] = atomicAdd(&bcur[t], hv);
    __syncthreads();
    for (int e = e0 + t; e < e1; e += 256) {
        int d = dst[e];
        int b = d >> 8;
        int pos = base[b] + atomicAdd(&lcur[b], 1);
        unsigned lo = ((unsigned)src[e] << 16) |
                      __half_as_ushort(__float2half_rn(pre_w[e]));
        uint2 r; r.x = lo; r.y = (unsigned)d;
        tmp[pos] = r;
    }
}

__global__ __launch_bounds__(256) void bucket_to_csr(
    const uint2* __restrict__ tmp, const int* __restrict__ bbase,
    const float* __restrict__ s_l, const float* __restrict__ s_r,
    int* __restrict__ offs, int* __restrict__ deg,
    unsigned int* __restrict__ sp_s, float* __restrict__ alpha_s, int N)
{
    __shared__ int h[256], excl[256], cur[256];
    int b = blockIdx.x;
    int t = threadIdx.x;
    int start = bbase[b], end = bbase[b + 1];
    h[t] = 0; cur[t] = 0;
    __syncthreads();
    for (int i = start + t; i < end; i += 256)
        atomicAdd(&h[tmp[i].y & 255], 1);
    __syncthreads();
    int x = h[t];
    excl[t] = x;
    __syncthreads();
    for (int off = 1; off < 256; off <<= 1) {
        int y = (t >= off) ? excl[t - off] : 0;
        __syncthreads();
        excl[t] += y;
        __syncthreads();
    }
    int ex = excl[t] - x;
    int n = (b << 8) + t;
    if (n < N) { offs[n] = start + ex; deg[n] = x; }
    __syncthreads();
    excl[t] = ex;
    __syncthreads();
    for (int i = start + t; i < end; i += 256) {
        uint2 r = tmp[i];
        int d8 = r.y & 255;
        int pos = start + excl[d8] + atomicAdd(&cur[d8], 1);
        sp_s[pos] = r.x;
    }
    __syncthreads();
    if (n < N && x > 0) {
        int s0 = start + ex;
        float srn = s_r[n];
        float m = -INFINITY;
        for (int j = 0; j < x; j++) {
            unsigned rec = sp_s[s0 + j];
            float pw = __half2float(__ushort_as_half((unsigned short)(rec & 0xffffu)));
            float ea = fmaf(pw, s_l[rec >> 16], srn);
            ea = ea > 0.f ? ea : SLOPE * ea;
            alpha_s[s0 + j] = ea;
            m = fmaxf(m, ea);
        }
        float ssum = 0.f;
        for (int j = 0; j < x; j++) {
            float exv = __expf(alpha_s[s0 + j] - m);
            alpha_s[s0 + j] = exv;
            ssum += exv;
        }
        float inv = 1.f / fmaxf(ssum, 1e-16f);
        for (int j = 0; j < x; j++) alpha_s[s0 + j] *= inv;
    }
}

// ---------------------------------------------------------------------------
// Aggregate: one wave per dst node, lane = feature dim (unchanged).
// ---------------------------------------------------------------------------
__global__ __launch_bounds__(256) void aggregate(
    const int* __restrict__ offs, const int* __restrict__ deg_a,
    const unsigned int* __restrict__ sp_s, const float* __restrict__ alpha_s,
    const __half2* __restrict__ zu,
    const float* __restrict__ t_gr, const float* __restrict__ g0,
    const float* __restrict__ gm,
    float* __restrict__ out, int N)
{
    int n = __builtin_amdgcn_readfirstlane((blockIdx.x * 256 + threadIdx.x) >> 6);
    int k = threadIdx.x & 63;
    if (n >= N) return;
    int deg = deg_a[n];
    size_t outIdx = (size_t)n * DIM + k;
    if (deg == 0) { out[outIdx] = 0.f; return; }
    int start = offs[n];

    float hk = 0.f, mfk = -INFINITY, msum = 0.f;
    int j = 0;
    for (; j + 8 <= deg; j += 8) {
        int p = start + j;
        unsigned int rec[8]; float al[8]; __half2 q[8]; float ts[8];
#pragma unroll
        for (int i = 0; i < 8; i++) rec[i] = sp_s[p + i];
#pragma unroll
        for (int i = 0; i < 8; i++) al[i] = alpha_s[p + i];
#pragma unroll
        for (int i = 0; i < 8; i++) q[i] = zu[(size_t)(rec[i] >> 16) * DIM + k];
#pragma unroll
        for (int i = 0; i < 8; i++) ts[i] = t_gr[rec[i] >> 16];
#pragma unroll
        for (int i = 0; i < 8; i++) {
            float2 f = __half22float2(q[i]);
            float pw = __half2float(__ushort_as_half((unsigned short)(rec[i] & 0xffffu)));
            hk = fmaf(al[i], f.x, hk);
            mfk = fmaxf(mfk, pw * f.y);
            msum = fmaf(pw, ts[i], msum);
        }
    }
    for (; j + 4 <= deg; j += 4) {
        int p = start + j;
        unsigned int rec[4]; float al[4]; __half2 q[4]; float ts[4];
#pragma unroll
        for (int i = 0; i < 4; i++) rec[i] = sp_s[p + i];
#pragma unroll
        for (int i = 0; i < 4; i++) al[i] = alpha_s[p + i];
#pragma unroll
        for (int i = 0; i < 4; i++) q[i] = zu[(size_t)(rec[i] >> 16) * DIM + k];
#pragma unroll
        for (int i = 0; i < 4; i++) ts[i] = t_gr[rec[i] >> 16];
#pragma unroll
        for (int i = 0; i < 4; i++) {
            float2 f = __half22float2(q[i]);
            float pw = __half2float(__ushort_as_half((unsigned short)(rec[i] & 0xffffu)));
            hk = fmaf(al[i], f.x, hk);
            mfk = fmaxf(mfk, pw * f.y);
            msum = fmaf(pw, ts[i], msum);
        }
    }
    for (; j < deg; j++) {
        int p = start + j;
        unsigned int rec = sp_s[p];
        float al = alpha_s[p];
        __half2 q = zu[(size_t)(rec >> 16) * DIM + k];
        float pw = __half2float(__ushort_as_half((unsigned short)(rec & 0xffffu)));
        float2 f = __half22float2(q);
        hk = fmaf(al, f.x, hk);
        mfk = fmaxf(mfk, pw * f.y);
        msum = fmaf(pw, t_gr[rec >> 16], msum);
    }
    float r = gm[k] * mfk;
    for (int off = 32; off; off >>= 1) r += __shfl_down(r, off, 64);
    r = __shfl(r, 0, 64);
    float meanDot = msum / (float)deg;
    float xg = g0[n] + r + meanDot;
    float gate = 1.f / (1.f + __expf(-xg));
    out[outIdx] = gate * hk;
}

// ---------------------------------------------------------------------------
extern "C" void kernel_launch(void* const* d_in, const int* in_sizes, int n_in,
                              void* d_out, int out_size, void* d_ws, size_t ws_size,
                              hipStream_t stream)
{
    const float* v     = (const float*)d_in[0];
    const float* pre_w = (const float*)d_in[1];
    const int*   src   = (const int*)d_in[2];
    const int*   dst   = (const int*)d_in[3];
    const float* Wa    = (const float*)d_in[4];
    const float* a_l   = (const float*)d_in[5];
    const float* a_r   = (const float*)d_in[6];
    const float* Wg    = (const float*)d_in[7];
    const float* gl    = (const float*)d_in[8];
    const float* gm    = (const float*)d_in[9];
    const float* gr    = (const float*)d_in[10];
    int N = in_sizes[0] / DIM;
    int E = in_sizes[2];
    int nbuck = (N + 255) >> 8;

    // workspace layout (~27 MB)
    char* ws    = (char*)d_ws;
    __half2* zu = (__half2*)ws;                       // N*DIM*4B = 12.8MB
    float* s_l  = (float*)(ws + (size_t)N * DIM * 4);
    float* s_r  = s_l + N;
    float* t_gr = s_r + N;
    float* g0   = t_gr + N;
    int* offs   = (int*)(g0 + N);
    int* deg    = offs + N;
    int* ghist  = deg + N;                            // 256
    int* bbase  = ghist + 256;                        // 257
    int* bcur   = bbase + 260;                        // 256
    uint2* tmp  = (uint2*)(bcur + 260);               // E*8B = 6.4MB
    unsigned int* sp_s = (unsigned int*)(tmp + E);    // E*4B
    float* alpha_s = (float*)(sp_s + E);              // E*4B

    hipMemsetAsync(ghist, 0, 256 * sizeof(int), stream);

    node_proj<<<(N + 63) / 64, 256, 0, stream>>>(
        v, Wa, Wg, a_l, a_r, gl, gr, zu, s_l, s_r, t_gr, g0, N);

    bucket_hist<<<(E + 2047) / 2048, 256, 0, stream>>>(dst, ghist, E);
    bucket_scan<<<1, 256, 0, stream>>>(ghist, bbase, bcur);
    bucket_scatter<<<(E + P1_CHUNK - 1) / P1_CHUNK, 256, 0, stream>>>(
        src, dst, pre_w, bcur, tmp, E);
    bucket_to_csr<<<nbuck, 256, 0, stream>>>(
        tmp, bbase, s_l, s_r, offs, deg, sp_s, alpha_s, N);

    aggregate<<<(N + 3) / 4, 256, 0, stream>>>(
        offs, deg, sp_s, alpha_s, zu, t_gr, g0, gm, (float*)d_out, N);
}

// Round 8
// 193.409 us; speedup vs baseline: 1.4300x; 1.0235x over previous
//
#include <hip/hip_runtime.h>
#include <hip/hip_fp16.h>

#define DIM 64
#define SLOPE 0.01f
#define P1_CHUNK 4096
#define LDH 72   // LDS row stride in halves (64 + 8 pad)

typedef _Float16 half8 __attribute__((ext_vector_type(8)));
typedef float float4v __attribute__((ext_vector_type(4)));

// ---------------------------------------------------------------------------
// Kernel 1: per-node projections via MFMA (f32_16x16x32_f16). Unchanged.
// ---------------------------------------------------------------------------
__global__ __launch_bounds__(256) void node_proj(
    const float* __restrict__ v, const float* __restrict__ Wa,
    const float* __restrict__ Wg, const float* __restrict__ a_l,
    const float* __restrict__ a_r, const float* __restrict__ gl,
    const float* __restrict__ gr,
    __half2* __restrict__ zu,
    float* __restrict__ s_l, float* __restrict__ s_r,
    float* __restrict__ t_gr, float* __restrict__ g0, int N)
{
    __shared__ _Float16 vt[64 * LDH];
    __shared__ _Float16 wah[64 * LDH];
    __shared__ _Float16 wgh[64 * LDH];
    __shared__ _Float16 bx[16 * LDH];
    int tid = threadIdx.x;
    int base = blockIdx.x * 64;

    {
        int r = tid >> 2, i0 = (tid & 3) * 16;
        int n = base + r;
        _Float16* dv = &vt[r * LDH + i0];
        if (n < N) {
            const float4* sv = (const float4*)(v + (size_t)n * DIM + i0);
#pragma unroll
            for (int c = 0; c < 4; c++) {
                float4 q = sv[c];
                dv[4*c+0] = (_Float16)q.x; dv[4*c+1] = (_Float16)q.y;
                dv[4*c+2] = (_Float16)q.z; dv[4*c+3] = (_Float16)q.w;
            }
        } else {
#pragma unroll
            for (int c = 0; c < 16; c++) dv[c] = (_Float16)0.f;
        }
        const float4* sa = (const float4*)(Wa + (size_t)r * DIM + i0);
        const float4* sg = (const float4*)(Wg + (size_t)r * DIM + i0);
        _Float16* da = &wah[r * LDH + i0];
        _Float16* dg = &wgh[r * LDH + i0];
#pragma unroll
        for (int c = 0; c < 4; c++) {
            float4 qa = sa[c], qg = sg[c];
            da[4*c+0] = (_Float16)qa.x; da[4*c+1] = (_Float16)qa.y;
            da[4*c+2] = (_Float16)qa.z; da[4*c+3] = (_Float16)qa.w;
            dg[4*c+0] = (_Float16)qg.x; dg[4*c+1] = (_Float16)qg.y;
            dg[4*c+2] = (_Float16)qg.z; dg[4*c+3] = (_Float16)qg.w;
        }
        if (tid < 64)       bx[0 * LDH + tid] = (_Float16)gl[tid];
        else if (tid < 128) bx[1 * LDH + (tid - 64)] = (_Float16)gr[tid - 64];
        for (int x = tid; x < 12 * 64; x += 256)
            bx[(4 + (x >> 6)) * LDH + (x & 63)] = (_Float16)0.f;
    }
    __syncthreads();
    if (tid < 64) {
        int i = tid;
        float acc = 0.f;
        for (int k = 0; k < 64; k++) acc = fmaf(a_l[k], (float)wah[k * LDH + i], acc);
        bx[2 * LDH + i] = (_Float16)acc;
    } else if (tid < 128) {
        int i = tid - 64;
        float acc = 0.f;
        for (int k = 0; k < 64; k++) acc = fmaf(a_r[k], (float)wah[k * LDH + i], acc);
        bx[3 * LDH + i] = (_Float16)acc;
    }
    __syncthreads();

    int lane = tid & 63;
    int m0 = (tid >> 6) * 16;
    int rb = lane & 15;
    int q  = lane >> 4;

    half8 a_lo = *(const half8*)&vt[(m0 + rb) * LDH + q * 8];
    half8 a_hi = *(const half8*)&vt[(m0 + rb) * LDH + 32 + q * 8];

    float4v zacc[4], uacc[4], sacc;
#pragma unroll
    for (int tc = 0; tc < 4; tc++) { zacc[tc] = (float4v)0.f; uacc[tc] = (float4v)0.f; }
    sacc = (float4v)0.f;

#pragma unroll
    for (int tc = 0; tc < 4; tc++) {
        int c0 = tc * 16;
        half8 blo = *(const half8*)&wah[(c0 + rb) * LDH + q * 8];
        half8 bhi = *(const half8*)&wah[(c0 + rb) * LDH + 32 + q * 8];
        zacc[tc] = __builtin_amdgcn_mfma_f32_16x16x32_f16(a_lo, blo, zacc[tc], 0, 0, 0);
        zacc[tc] = __builtin_amdgcn_mfma_f32_16x16x32_f16(a_hi, bhi, zacc[tc], 0, 0, 0);
        half8 glo = *(const half8*)&wgh[(c0 + rb) * LDH + q * 8];
        half8 ghi = *(const half8*)&wgh[(c0 + rb) * LDH + 32 + q * 8];
        uacc[tc] = __builtin_amdgcn_mfma_f32_16x16x32_f16(a_lo, glo, uacc[tc], 0, 0, 0);
        uacc[tc] = __builtin_amdgcn_mfma_f32_16x16x32_f16(a_hi, ghi, uacc[tc], 0, 0, 0);
    }
    {
        half8 blo = *(const half8*)&bx[rb * LDH + q * 8];
        half8 bhi = *(const half8*)&bx[rb * LDH + 32 + q * 8];
        sacc = __builtin_amdgcn_mfma_f32_16x16x32_f16(a_lo, blo, sacc, 0, 0, 0);
        sacc = __builtin_amdgcn_mfma_f32_16x16x32_f16(a_hi, bhi, sacc, 0, 0, 0);
    }

#pragma unroll
    for (int r = 0; r < 4; r++) {
        int n = base + m0 + q * 4 + r;
        if (n < N) {
#pragma unroll
            for (int tc = 0; tc < 4; tc++)
                zu[(size_t)n * DIM + tc * 16 + rb] = __floats2half2_rn(zacc[tc][r], uacc[tc][r]);
        }
    }
    if (rb < 4) {
        float* arr = (rb == 0) ? g0 : (rb == 1) ? t_gr : (rb == 2) ? s_l : s_r;
#pragma unroll
        for (int r = 0; r < 4; r++) {
            int n = base + m0 + q * 4 + r;
            if (n < N) arr[n] = sacc[r];
        }
    }
}

// ---------------------------------------------------------------------------
// Bucketed CSR build, bucket = dst>>8. bucket_scan kernel removed: both
// consumers recompute the 256-wide prefix scan of ghist in LDS (~100ns).
// ---------------------------------------------------------------------------
__global__ __launch_bounds__(256) void bucket_hist(
    const int* __restrict__ dst, int* __restrict__ ghist, int E)
{
    __shared__ int h[256];
    h[threadIdx.x] = 0;
    __syncthreads();
    int stride = gridDim.x * 256;
    for (int e = blockIdx.x * 256 + threadIdx.x; e < E; e += stride)
        atomicAdd(&h[dst[e] >> 8], 1);
    __syncthreads();
    int hv = h[threadIdx.x];
    if (hv) atomicAdd(&ghist[threadIdx.x], hv);
}

// Phase 1: scatter into bucket regions. In-block scan of ghist -> bbase;
// zero-based global reservation counters bcur0.
__global__ __launch_bounds__(256) void bucket_scatter(
    const int* __restrict__ src, const int* __restrict__ dst,
    const float* __restrict__ pre_w, const int* __restrict__ ghist,
    int* __restrict__ bcur0, uint2* __restrict__ tmp, int E)
{
    __shared__ int h[256], lcur[256], wbase[256], sc[256];
    int t = threadIdx.x;
    h[t] = 0; lcur[t] = 0;
    __syncthreads();
    int e0 = blockIdx.x * P1_CHUNK;
    int e1 = e0 + P1_CHUNK; if (e1 > E) e1 = E;
    for (int e = e0 + t; e < e1; e += 256)
        atomicAdd(&h[dst[e] >> 8], 1);
    __syncthreads();
    int hv = h[t];
    int gb = hv ? atomicAdd(&bcur0[t], hv) : 0;   // within-bucket reservation
    // in-block exclusive scan of ghist
    int gh = ghist[t];
    sc[t] = gh;
    __syncthreads();
    for (int off = 1; off < 256; off <<= 1) {
        int y = (t >= off) ? sc[t - off] : 0;
        __syncthreads();
        sc[t] += y;
        __syncthreads();
    }
    wbase[t] = (sc[t] - gh) + gb;                 // bucket base + reservation
    __syncthreads();
    for (int e = e0 + t; e < e1; e += 256) {
        int d = dst[e];
        int b = d >> 8;
        int pos = wbase[b] + atomicAdd(&lcur[b], 1);
        unsigned lo = ((unsigned)src[e] << 16) |
                      __half_as_ushort(__float2half_rn(pre_w[e]));
        uint2 r; r.x = lo; r.y = (unsigned)d;
        tmp[pos] = r;
    }
}

// Phase 2: one block per bucket -> per-node offs/deg + CSR placement +
// fused 2-pass softmax (unnormalized exp; 1/denom stored per node).
__global__ __launch_bounds__(256) void bucket_to_csr(
    const uint2* __restrict__ tmp, const int* __restrict__ ghist,
    const float* __restrict__ s_l, const float* __restrict__ s_r,
    int* __restrict__ offs, int* __restrict__ deg,
    unsigned int* __restrict__ sp_s, float* __restrict__ alpha_s,
    float* __restrict__ inv_d, int N)
{
    __shared__ int h[256], excl[256], cur[256], sc[256];
    int b = blockIdx.x;
    int t = threadIdx.x;
    // in-block inclusive scan of ghist -> bucket bounds (broadcast reads)
    int gh = ghist[t];
    sc[t] = gh;
    __syncthreads();
    for (int off = 1; off < 256; off <<= 1) {
        int y = (t >= off) ? sc[t - off] : 0;
        __syncthreads();
        sc[t] += y;
        __syncthreads();
    }
    int start = (b == 0) ? 0 : sc[b - 1];
    int end = sc[b];
    h[t] = 0; cur[t] = 0;
    __syncthreads();
    for (int i = start + t; i < end; i += 256)
        atomicAdd(&h[tmp[i].y & 255], 1);
    __syncthreads();
    int x = h[t];
    excl[t] = x;
    __syncthreads();
    for (int off = 1; off < 256; off <<= 1) {
        int y = (t >= off) ? excl[t - off] : 0;
        __syncthreads();
        excl[t] += y;
        __syncthreads();
    }
    int ex = excl[t] - x;
    int n = (b << 8) + t;
    if (n < N) { offs[n] = start + ex; deg[n] = x; }
    __syncthreads();
    excl[t] = ex;
    __syncthreads();
    for (int i = start + t; i < end; i += 256) {
        uint2 r = tmp[i];
        int d8 = r.y & 255;
        int pos = start + excl[d8] + atomicAdd(&cur[d8], 1);
        sp_s[pos] = r.x;
    }
    __syncthreads();
    // fused softmax, 2 passes; normalization deferred to aggregate
    if (n < N && x > 0) {
        int s0 = start + ex;
        float srn = s_r[n];
        float m = -INFINITY;
        for (int j = 0; j < x; j++) {
            unsigned rec = sp_s[s0 + j];
            float pw = __half2float(__ushort_as_half((unsigned short)(rec & 0xffffu)));
            float ea = fmaf(pw, s_l[rec >> 16], srn);
            ea = ea > 0.f ? ea : SLOPE * ea;
            alpha_s[s0 + j] = ea;
            m = fmaxf(m, ea);
        }
        float ssum = 0.f;
        for (int j = 0; j < x; j++) {
            float exv = __expf(alpha_s[s0 + j] - m);
            alpha_s[s0 + j] = exv;      // unnormalized
            ssum += exv;
        }
        inv_d[n] = 1.f / fmaxf(ssum, 1e-16f);
    }
}

// ---------------------------------------------------------------------------
// Aggregate: one wave per dst node, lane = feature dim. Unroll 16 -> 16
// independent gathers in flight (deg ~ Poisson(16)). hk scaled by inv_d[n].
// ---------------------------------------------------------------------------
__global__ __launch_bounds__(256) void aggregate(
    const int* __restrict__ offs, const int* __restrict__ deg_a,
    const unsigned int* __restrict__ sp_s, const float* __restrict__ alpha_s,
    const __half2* __restrict__ zu,
    const float* __restrict__ t_gr, const float* __restrict__ g0,
    const float* __restrict__ gm, const float* __restrict__ inv_d,
    float* __restrict__ out, int N)
{
    int n = __builtin_amdgcn_readfirstlane((blockIdx.x * 256 + threadIdx.x) >> 6);
    int k = threadIdx.x & 63;
    if (n >= N) return;
    int deg = deg_a[n];
    size_t outIdx = (size_t)n * DIM + k;
    if (deg == 0) { out[outIdx] = 0.f; return; }
    int start = offs[n];

    float hk = 0.f, mfk = -INFINITY, msum = 0.f;
    int j = 0;
    for (; j + 16 <= deg; j += 16) {
        int p = start + j;
        unsigned int rec[16]; float al[16]; __half2 q[16]; float ts[16];
#pragma unroll
        for (int i = 0; i < 16; i++) rec[i] = sp_s[p + i];
#pragma unroll
        for (int i = 0; i < 16; i++) al[i] = alpha_s[p + i];
#pragma unroll
        for (int i = 0; i < 16; i++) q[i] = zu[(size_t)(rec[i] >> 16) * DIM + k];
#pragma unroll
        for (int i = 0; i < 16; i++) ts[i] = t_gr[rec[i] >> 16];
#pragma unroll
        for (int i = 0; i < 16; i++) {
            float2 f = __half22float2(q[i]);
            float pw = __half2float(__ushort_as_half((unsigned short)(rec[i] & 0xffffu)));
            hk = fmaf(al[i], f.x, hk);
            mfk = fmaxf(mfk, pw * f.y);
            msum = fmaf(pw, ts[i], msum);
        }
    }
    for (; j + 8 <= deg; j += 8) {
        int p = start + j;
        unsigned int rec[8]; float al[8]; __half2 q[8]; float ts[8];
#pragma unroll
        for (int i = 0; i < 8; i++) rec[i] = sp_s[p + i];
#pragma unroll
        for (int i = 0; i < 8; i++) al[i] = alpha_s[p + i];
#pragma unroll
        for (int i = 0; i < 8; i++) q[i] = zu[(size_t)(rec[i] >> 16) * DIM + k];
#pragma unroll
        for (int i = 0; i < 8; i++) ts[i] = t_gr[rec[i] >> 16];
#pragma unroll
        for (int i = 0; i < 8; i++) {
            float2 f = __half22float2(q[i]);
            float pw = __half2float(__ushort_as_half((unsigned short)(rec[i] & 0xffffu)));
            hk = fmaf(al[i], f.x, hk);
            mfk = fmaxf(mfk, pw * f.y);
            msum = fmaf(pw, ts[i], msum);
        }
    }
    for (; j + 4 <= deg; j += 4) {
        int p = start + j;
        unsigned int rec[4]; float al[4]; __half2 q[4]; float ts[4];
#pragma unroll
        for (int i = 0; i < 4; i++) rec[i] = sp_s[p + i];
#pragma unroll
        for (int i = 0; i < 4; i++) al[i] = alpha_s[p + i];
#pragma unroll
        for (int i = 0; i < 4; i++) q[i] = zu[(size_t)(rec[i] >> 16) * DIM + k];
#pragma unroll
        for (int i = 0; i < 4; i++) ts[i] = t_gr[rec[i] >> 16];
#pragma unroll
        for (int i = 0; i < 4; i++) {
            float2 f = __half22float2(q[i]);
            float pw = __half2float(__ushort_as_half((unsigned short)(rec[i] & 0xffffu)));
            hk = fmaf(al[i], f.x, hk);
            mfk = fmaxf(mfk, pw * f.y);
            msum = fmaf(pw, ts[i], msum);
        }
    }
    for (; j < deg; j++) {
        int p = start + j;
        unsigned int rec = sp_s[p];
        float al = alpha_s[p];
        __half2 q = zu[(size_t)(rec >> 16) * DIM + k];
        float pw = __half2float(__ushort_as_half((unsigned short)(rec & 0xffffu)));
        float2 f = __half22float2(q);
        hk = fmaf(al, f.x, hk);
        mfk = fmaxf(mfk, pw * f.y);
        msum = fmaf(pw, t_gr[rec >> 16], msum);
    }
    float r = gm[k] * mfk;
    for (int off = 32; off; off >>= 1) r += __shfl_down(r, off, 64);
    r = __shfl(r, 0, 64);
    float invd = inv_d[n];
    float meanDot = msum / (float)deg;
    float xg = g0[n] + r + meanDot;
    float gate = 1.f / (1.f + __expf(-xg));
    out[outIdx] = gate * hk * invd;
}

// ---------------------------------------------------------------------------
extern "C" void kernel_launch(void* const* d_in, const int* in_sizes, int n_in,
                              void* d_out, int out_size, void* d_ws, size_t ws_size,
                              hipStream_t stream)
{
    const float* v     = (const float*)d_in[0];
    const float* pre_w = (const float*)d_in[1];
    const int*   src   = (const int*)d_in[2];
    const int*   dst   = (const int*)d_in[3];
    const float* Wa    = (const float*)d_in[4];
    const float* a_l   = (const float*)d_in[5];
    const float* a_r   = (const float*)d_in[6];
    const float* Wg    = (const float*)d_in[7];
    const float* gl    = (const float*)d_in[8];
    const float* gm    = (const float*)d_in[9];
    const float* gr    = (const float*)d_in[10];
    int N = in_sizes[0] / DIM;
    int E = in_sizes[2];
    int nbuck = (N + 255) >> 8;

    // workspace layout (~27 MB)
    char* ws    = (char*)d_ws;
    __half2* zu = (__half2*)ws;                       // N*DIM*4B
    float* s_l  = (float*)(ws + (size_t)N * DIM * 4);
    float* s_r  = s_l + N;
    float* t_gr = s_r + N;
    float* g0   = t_gr + N;
    float* invd = g0 + N;
    int* offs   = (int*)(invd + N);
    int* deg    = offs + N;
    int* ghist  = deg + N;                            // 256 (zeroed)
    int* bcur0  = ghist + 256;                        // 256 (zeroed)
    uint2* tmp  = (uint2*)(bcur0 + 256);              // E*8B
    unsigned int* sp_s = (unsigned int*)(tmp + E);    // E*4B
    float* alpha_s = (float*)(sp_s + E);              // E*4B

    hipMemsetAsync(ghist, 0, 512 * sizeof(int), stream);

    node_proj<<<(N + 63) / 64, 256, 0, stream>>>(
        v, Wa, Wg, a_l, a_r, gl, gr, zu, s_l, s_r, t_gr, g0, N);

    bucket_hist<<<(E + 2047) / 2048, 256, 0, stream>>>(dst, ghist, E);
    bucket_scatter<<<(E + P1_CHUNK - 1) / P1_CHUNK, 256, 0, stream>>>(
        src, dst, pre_w, ghist, bcur0, tmp, E);
    bucket_to_csr<<<nbuck, 256, 0, stream>>>(
        tmp, ghist, s_l, s_r, offs, deg, sp_s, alpha_s, invd, N);

    aggregate<<<(N + 3) / 4, 256, 0, stream>>>(
        offs, deg, sp_s, alpha_s, zu, t_gr, g0, gm, invd, (float*)d_out, N);
}

// Round 9
// 168.143 us; speedup vs baseline: 1.6448x; 1.1503x over previous
//
#include <hip/hip_runtime.h>
#include <hip/hip_fp16.h>

#define DIM 64
#define SLOPE 0.01f
#define P1_CHUNK 4096
#define CAP 8192     // fixed per-bucket capacity (expected 4096, 64-sigma margin)
#define LDH 72       // LDS row stride in halves (64 + 8 pad)

typedef _Float16 half8 __attribute__((ext_vector_type(8)));
typedef float float4v __attribute__((ext_vector_type(4)));

// ---------------------------------------------------------------------------
// Kernel 1: per-node projections via MFMA (f32_16x16x32_f16). Unchanged.
// ---------------------------------------------------------------------------
__global__ __launch_bounds__(256) void node_proj(
    const float* __restrict__ v, const float* __restrict__ Wa,
    const float* __restrict__ Wg, const float* __restrict__ a_l,
    const float* __restrict__ a_r, const float* __restrict__ gl,
    const float* __restrict__ gr,
    __half2* __restrict__ zu,
    float* __restrict__ s_l, float* __restrict__ s_r,
    float* __restrict__ t_gr, float* __restrict__ g0, int N)
{
    __shared__ _Float16 vt[64 * LDH];
    __shared__ _Float16 wah[64 * LDH];
    __shared__ _Float16 wgh[64 * LDH];
    __shared__ _Float16 bx[16 * LDH];
    int tid = threadIdx.x;
    int base = blockIdx.x * 64;

    {
        int r = tid >> 2, i0 = (tid & 3) * 16;
        int n = base + r;
        _Float16* dv = &vt[r * LDH + i0];
        if (n < N) {
            const float4* sv = (const float4*)(v + (size_t)n * DIM + i0);
#pragma unroll
            for (int c = 0; c < 4; c++) {
                float4 q = sv[c];
                dv[4*c+0] = (_Float16)q.x; dv[4*c+1] = (_Float16)q.y;
                dv[4*c+2] = (_Float16)q.z; dv[4*c+3] = (_Float16)q.w;
            }
        } else {
#pragma unroll
            for (int c = 0; c < 16; c++) dv[c] = (_Float16)0.f;
        }
        const float4* sa = (const float4*)(Wa + (size_t)r * DIM + i0);
        const float4* sg = (const float4*)(Wg + (size_t)r * DIM + i0);
        _Float16* da = &wah[r * LDH + i0];
        _Float16* dg = &wgh[r * LDH + i0];
#pragma unroll
        for (int c = 0; c < 4; c++) {
            float4 qa = sa[c], qg = sg[c];
            da[4*c+0] = (_Float16)qa.x; da[4*c+1] = (_Float16)qa.y;
            da[4*c+2] = (_Float16)qa.z; da[4*c+3] = (_Float16)qa.w;
            dg[4*c+0] = (_Float16)qg.x; dg[4*c+1] = (_Float16)qg.y;
            dg[4*c+2] = (_Float16)qg.z; dg[4*c+3] = (_Float16)qg.w;
        }
        if (tid < 64)       bx[0 * LDH + tid] = (_Float16)gl[tid];
        else if (tid < 128) bx[1 * LDH + (tid - 64)] = (_Float16)gr[tid - 64];
        for (int x = tid; x < 12 * 64; x += 256)
            bx[(4 + (x >> 6)) * LDH + (x & 63)] = (_Float16)0.f;
    }
    __syncthreads();
    if (tid < 64) {
        int i = tid;
        float acc = 0.f;
        for (int k = 0; k < 64; k++) acc = fmaf(a_l[k], (float)wah[k * LDH + i], acc);
        bx[2 * LDH + i] = (_Float16)acc;
    } else if (tid < 128) {
        int i = tid - 64;
        float acc = 0.f;
        for (int k = 0; k < 64; k++) acc = fmaf(a_r[k], (float)wah[k * LDH + i], acc);
        bx[3 * LDH + i] = (_Float16)acc;
    }
    __syncthreads();

    int lane = tid & 63;
    int m0 = (tid >> 6) * 16;
    int rb = lane & 15;
    int q  = lane >> 4;

    half8 a_lo = *(const half8*)&vt[(m0 + rb) * LDH + q * 8];
    half8 a_hi = *(const half8*)&vt[(m0 + rb) * LDH + 32 + q * 8];

    float4v zacc[4], uacc[4], sacc;
#pragma unroll
    for (int tc = 0; tc < 4; tc++) { zacc[tc] = (float4v)0.f; uacc[tc] = (float4v)0.f; }
    sacc = (float4v)0.f;

#pragma unroll
    for (int tc = 0; tc < 4; tc++) {
        int c0 = tc * 16;
        half8 blo = *(const half8*)&wah[(c0 + rb) * LDH + q * 8];
        half8 bhi = *(const half8*)&wah[(c0 + rb) * LDH + 32 + q * 8];
        zacc[tc] = __builtin_amdgcn_mfma_f32_16x16x32_f16(a_lo, blo, zacc[tc], 0, 0, 0);
        zacc[tc] = __builtin_amdgcn_mfma_f32_16x16x32_f16(a_hi, bhi, zacc[tc], 0, 0, 0);
        half8 glo = *(const half8*)&wgh[(c0 + rb) * LDH + q * 8];
        half8 ghi = *(const half8*)&wgh[(c0 + rb) * LDH + 32 + q * 8];
        uacc[tc] = __builtin_amdgcn_mfma_f32_16x16x32_f16(a_lo, glo, uacc[tc], 0, 0, 0);
        uacc[tc] = __builtin_amdgcn_mfma_f32_16x16x32_f16(a_hi, ghi, uacc[tc], 0, 0, 0);
    }
    {
        half8 blo = *(const half8*)&bx[rb * LDH + q * 8];
        half8 bhi = *(const half8*)&bx[rb * LDH + 32 + q * 8];
        sacc = __builtin_amdgcn_mfma_f32_16x16x32_f16(a_lo, blo, sacc, 0, 0, 0);
        sacc = __builtin_amdgcn_mfma_f32_16x16x32_f16(a_hi, bhi, sacc, 0, 0, 0);
    }

#pragma unroll
    for (int r = 0; r < 4; r++) {
        int n = base + m0 + q * 4 + r;
        if (n < N) {
#pragma unroll
            for (int tc = 0; tc < 4; tc++)
                zu[(size_t)n * DIM + tc * 16 + rb] = __floats2half2_rn(zacc[tc][r], uacc[tc][r]);
        }
    }
    if (rb < 4) {
        float* arr = (rb == 0) ? g0 : (rb == 1) ? t_gr : (rb == 2) ? s_l : s_r;
#pragma unroll
        for (int r = 0; r < 4; r++) {
            int n = base + m0 + q * 4 + r;
            if (n < N) arr[n] = sacc[r];
        }
    }
}

// ---------------------------------------------------------------------------
// Phase 1: scatter edges into FIXED-CAPACITY bucket regions (bucket=dst>>8,
// region = tmp[b*CAP ..]). Per-block LDS hist -> one global reservation
// atomic per (block,bucket). No pre-pass over dst needed (bucket_hist and
// the ghist scan are gone).
// ---------------------------------------------------------------------------
__global__ __launch_bounds__(256) void bucket_scatter(
    const int* __restrict__ src, const int* __restrict__ dst,
    const float* __restrict__ pre_w,
    int* __restrict__ bcur0, uint2* __restrict__ tmp, int E)
{
    __shared__ int h[256], lcur[256], wbase[256];
    int t = threadIdx.x;
    h[t] = 0; lcur[t] = 0;
    __syncthreads();
    int e0 = blockIdx.x * P1_CHUNK;
    int e1 = e0 + P1_CHUNK; if (e1 > E) e1 = E;
    for (int e = e0 + t; e < e1; e += 256)
        atomicAdd(&h[dst[e] >> 8], 1);            // LDS atomic
    __syncthreads();
    int hv = h[t];
    wbase[t] = hv ? atomicAdd(&bcur0[t], hv) : 0; // one global atomic/bucket
    __syncthreads();
    for (int e = e0 + t; e < e1; e += 256) {
        int d = dst[e];                           // L1-hot reread
        int b = d >> 8;
        int pos = wbase[b] + atomicAdd(&lcur[b], 1);
        if (pos < CAP) {
            unsigned lo = ((unsigned)src[e] << 16) |
                          __half_as_ushort(__float2half_rn(pre_w[e]));
            uint2 r; r.x = lo; r.y = (unsigned)d;
            tmp[(size_t)b * CAP + pos] = r;
        }
    }
}

// ---------------------------------------------------------------------------
// Phase 2: one block per bucket. In-block scan of final bucket counts ->
// compact CSR base; LDS hist of dst&255 -> per-node offs/deg; placement
// into the block-owned ~16KB sp_s window. (Softmax moved into aggregate.)
// ---------------------------------------------------------------------------
__global__ __launch_bounds__(256) void bucket_to_csr(
    const uint2* __restrict__ tmp, const int* __restrict__ bcur0,
    int* __restrict__ offs, int* __restrict__ deg,
    unsigned int* __restrict__ sp_s, int N)
{
    __shared__ int h[256], excl[256], cur[256], sc[256];
    int b = blockIdx.x;
    int t = threadIdx.x;
    int c = bcur0[t]; if (c > CAP) c = CAP;       // clamped count, bucket t
    sc[t] = c;
    __syncthreads();
    for (int off = 1; off < 256; off <<= 1) {
        int y = (t >= off) ? sc[t - off] : 0;
        __syncthreads();
        sc[t] += y;
        __syncthreads();
    }
    int start = (b == 0) ? 0 : sc[b - 1];
    int bcnt = sc[b] - start;
    const uint2* reg = tmp + (size_t)b * CAP;
    h[t] = 0; cur[t] = 0;
    __syncthreads();
    for (int i = t; i < bcnt; i += 256)
        atomicAdd(&h[reg[i].y & 255], 1);         // LDS atomic
    __syncthreads();
    int x = h[t];
    excl[t] = x;
    __syncthreads();
    for (int off = 1; off < 256; off <<= 1) {
        int y = (t >= off) ? excl[t - off] : 0;
        __syncthreads();
        excl[t] += y;
        __syncthreads();
    }
    int ex = excl[t] - x;
    int n = (b << 8) + t;
    if (n < N) { offs[n] = start + ex; deg[n] = x; }
    __syncthreads();
    excl[t] = ex;
    __syncthreads();
    for (int i = t; i < bcnt; i += 256) {
        uint2 r = reg[i];
        int d8 = r.y & 255;
        int pos = start + excl[d8] + atomicAdd(&cur[d8], 1);
        sp_s[pos] = r.x;
    }
}

// ---------------------------------------------------------------------------
// Aggregate with FUSED flash-style softmax. One wave per dst node.
// Phase A (per 64-edge chunk): lane j computes ea_j (s_l gather is one
// vector instruction per 64 edges), wave-reduce max -> weights in registers;
// msum accumulated here too. Phase B: per edge, {rec,w} broadcast via shfl,
// lane=feature zu gather, hk/mfk accumulate; online rescale across chunks.
// ---------------------------------------------------------------------------
__global__ __launch_bounds__(256) void aggregate(
    const int* __restrict__ offs, const int* __restrict__ deg_a,
    const unsigned int* __restrict__ sp_s,
    const __half2* __restrict__ zu,
    const float* __restrict__ s_l, const float* __restrict__ s_r,
    const float* __restrict__ t_gr, const float* __restrict__ g0,
    const float* __restrict__ gm,
    float* __restrict__ out, int N)
{
    int n = __builtin_amdgcn_readfirstlane((blockIdx.x * 256 + threadIdx.x) >> 6);
    int k = threadIdx.x & 63;
    if (n >= N) return;
    int deg = deg_a[n];
    size_t outIdx = (size_t)n * DIM + k;
    if (deg == 0) { out[outIdx] = 0.f; return; }
    int start = offs[n];
    float srn = s_r[n];

    float m = -INFINITY, denom = 0.f, hk = 0.f, mfk = -INFINITY, msum = 0.f;
    for (int c0 = 0; c0 < deg; c0 += 64) {
        int cn = deg - c0; if (cn > 64) cn = 64;
        unsigned rec = 0;
        float ea = -INFINITY;
        if (k < cn) {
            rec = sp_s[start + c0 + k];            // coalesced 256B load
            float pw = __half2float(__ushort_as_half((unsigned short)(rec & 0xffffu)));
            ea = fmaf(pw, s_l[rec >> 16], srn);    // parallel s_l gather
            ea = ea > 0.f ? ea : SLOPE * ea;       // leaky_relu
            msum = fmaf(pw, t_gr[rec >> 16], msum);
        }
        float mc = ea;
#pragma unroll
        for (int off = 32; off; off >>= 1) mc = fmaxf(mc, __shfl_xor(mc, off, 64));
        float mnew = fmaxf(m, mc);
        float scale = __expf(m - mnew);            // 0 on first chunk
        float w = __expf(ea - mnew);               // 0 for lanes >= cn
        float sw = w;
#pragma unroll
        for (int off = 32; off; off >>= 1) sw += __shfl_xor(sw, off, 64);
        denom = denom * scale + sw;
        hk *= scale;
        m = mnew;
        int j = 0;
        for (; j + 8 <= cn; j += 8) {
            unsigned r8[8]; float w8[8]; __half2 q8[8];
#pragma unroll
            for (int i = 0; i < 8; i++) {
                r8[i] = __shfl(rec, j + i, 64);
                w8[i] = __shfl(w, j + i, 64);
            }
#pragma unroll
            for (int i = 0; i < 8; i++) q8[i] = zu[(size_t)(r8[i] >> 16) * DIM + k];
#pragma unroll
            for (int i = 0; i < 8; i++) {
                float2 f = __half22float2(q8[i]);
                float pwj = __half2float(__ushort_as_half((unsigned short)(r8[i] & 0xffffu)));
                hk = fmaf(w8[i], f.x, hk);
                mfk = fmaxf(mfk, pwj * f.y);
            }
        }
        for (; j < cn; j++) {
            unsigned rj = __shfl(rec, j, 64);
            float wj = __shfl(w, j, 64);
            __half2 q = zu[(size_t)(rj >> 16) * DIM + k];
            float2 f = __half22float2(q);
            float pwj = __half2float(__ushort_as_half((unsigned short)(rj & 0xffffu)));
            hk = fmaf(wj, f.x, hk);
            mfk = fmaxf(mfk, pwj * f.y);
        }
    }
#pragma unroll
    for (int off = 32; off; off >>= 1) msum += __shfl_xor(msum, off, 64);
    float r = gm[k] * mfk;
#pragma unroll
    for (int off = 32; off; off >>= 1) r += __shfl_down(r, off, 64);
    r = __shfl(r, 0, 64);
    float meanDot = msum / (float)deg;
    float xg = g0[n] + r + meanDot;
    float gate = 1.f / (1.f + __expf(-xg));
    out[outIdx] = gate * hk / fmaxf(denom, 1e-16f);
}

// ---------------------------------------------------------------------------
extern "C" void kernel_launch(void* const* d_in, const int* in_sizes, int n_in,
                              void* d_out, int out_size, void* d_ws, size_t ws_size,
                              hipStream_t stream)
{
    const float* v     = (const float*)d_in[0];
    const float* pre_w = (const float*)d_in[1];
    const int*   src   = (const int*)d_in[2];
    const int*   dst   = (const int*)d_in[3];
    const float* Wa    = (const float*)d_in[4];
    const float* a_l   = (const float*)d_in[5];
    const float* a_r   = (const float*)d_in[6];
    const float* Wg    = (const float*)d_in[7];
    const float* gl    = (const float*)d_in[8];
    const float* gm    = (const float*)d_in[9];
    const float* gr    = (const float*)d_in[10];
    int N = in_sizes[0] / DIM;
    int E = in_sizes[2];
    int nbuck = (N + 255) >> 8;

    // workspace layout (~30 MB)
    char* ws    = (char*)d_ws;
    __half2* zu = (__half2*)ws;                       // N*DIM*4B = 12.8MB
    float* s_l  = (float*)(ws + (size_t)N * DIM * 4);
    float* s_r  = s_l + N;
    float* t_gr = s_r + N;
    float* g0   = t_gr + N;
    int* offs   = (int*)(g0 + N);
    int* deg    = offs + N;
    int* bcur0  = deg + N;                            // 256 (zeroed)
    uint2* tmp  = (uint2*)(bcur0 + 256);              // nbuck*CAP*8B ~12.9MB
    unsigned int* sp_s = (unsigned int*)(tmp + (size_t)nbuck * CAP);  // E*4B

    hipMemsetAsync(bcur0, 0, 256 * sizeof(int), stream);

    node_proj<<<(N + 63) / 64, 256, 0, stream>>>(
        v, Wa, Wg, a_l, a_r, gl, gr, zu, s_l, s_r, t_gr, g0, N);

    bucket_scatter<<<(E + P1_CHUNK - 1) / P1_CHUNK, 256, 0, stream>>>(
        src, dst, pre_w, bcur0, tmp, E);

    bucket_to_csr<<<nbuck, 256, 0, stream>>>(
        tmp, bcur0, offs, deg, sp_s, N);

    aggregate<<<(N + 3) / 4, 256, 0, stream>>>(
        offs, deg, sp_s, zu, s_l, s_r, t_gr, g0, gm, (float*)d_out, N);
}

// Round 10
// 158.620 us; speedup vs baseline: 1.7436x; 1.0600x over previous
//
#include <hip/hip_runtime.h>
#include <hip/hip_fp16.h>

#define DIM 64
#define SLOPE 0.01f
#define P1_CHUNK 4096
#define CAP 8192     // fixed per-bucket capacity (expected 4096, 64-sigma margin)
#define LDH 72       // LDS row stride in halves (64 + 8 pad)

typedef _Float16 half8 __attribute__((ext_vector_type(8)));
typedef float float4v __attribute__((ext_vector_type(4)));

// ---------------------------------------------------------------------------
// Fused K1: blocks [0, scBlocks) run the bucket scatter (memory/atomic
// bound); blocks [scBlocks, ..) run the MFMA node projection (MFMA/LDS
// bound). Independent inputs, complementary pipes -> co-resident overlap.
// Shared memory is a union (branch is block-uniform).
//   proj outputs: zu (fp16 z|u packed), st (float2 {s_l, t_gr}), s_r, g0
//   scatter outputs: tmp bucket regions + bcur0 counts (bucket = dst>>8)
// ---------------------------------------------------------------------------
__global__ __launch_bounds__(256) void proj_scatter(
    const float* __restrict__ v, const float* __restrict__ Wa,
    const float* __restrict__ Wg, const float* __restrict__ a_l,
    const float* __restrict__ a_r, const float* __restrict__ gl,
    const float* __restrict__ gr,
    __half2* __restrict__ zu, float2* __restrict__ st,
    float* __restrict__ s_r, float* __restrict__ g0,
    const int* __restrict__ src, const int* __restrict__ dst,
    const float* __restrict__ pre_w,
    int* __restrict__ bcur0, uint2* __restrict__ tmp,
    int N, int E, int scBlocks)
{
    __shared__ char smem[(64 * 3 + 16) * LDH * 2];   // 29952 B
    int tid = threadIdx.x;

    if (blockIdx.x < scBlocks) {
        // ------------------ bucket scatter ------------------
        int* h    = (int*)smem;          // 256
        int* lcur = h + 256;             // 256
        int* wbase = lcur + 256;         // 256
        h[tid] = 0; lcur[tid] = 0;
        __syncthreads();
        int e0 = blockIdx.x * P1_CHUNK;
        int e1 = e0 + P1_CHUNK; if (e1 > E) e1 = E;
        for (int e = e0 + tid; e < e1; e += 256)
            atomicAdd(&h[dst[e] >> 8], 1);            // LDS atomic
        __syncthreads();
        int hv = h[tid];
        wbase[tid] = hv ? atomicAdd(&bcur0[tid], hv) : 0;
        __syncthreads();
        for (int e = e0 + tid; e < e1; e += 256) {
            int d = dst[e];                           // L1-hot reread
            int b = d >> 8;
            int pos = wbase[b] + atomicAdd(&lcur[b], 1);
            if (pos < CAP) {
                unsigned lo = ((unsigned)src[e] << 16) |
                              __half_as_ushort(__float2half_rn(pre_w[e]));
                uint2 r; r.x = lo; r.y = (unsigned)d;
                tmp[(size_t)b * CAP + pos] = r;
            }
        }
        return;
    }

    // ------------------ MFMA node projection ------------------
    _Float16* vt  = (_Float16*)smem;     // 64*LDH
    _Float16* wah = vt + 64 * LDH;
    _Float16* wgh = wah + 64 * LDH;
    _Float16* bx  = wgh + 64 * LDH;      // 16*LDH
    int base = (blockIdx.x - scBlocks) * 64;

    {
        int r = tid >> 2, i0 = (tid & 3) * 16;
        int n = base + r;
        _Float16* dv = &vt[r * LDH + i0];
        if (n < N) {
            const float4* sv = (const float4*)(v + (size_t)n * DIM + i0);
#pragma unroll
            for (int c = 0; c < 4; c++) {
                float4 q = sv[c];
                dv[4*c+0] = (_Float16)q.x; dv[4*c+1] = (_Float16)q.y;
                dv[4*c+2] = (_Float16)q.z; dv[4*c+3] = (_Float16)q.w;
            }
        } else {
#pragma unroll
            for (int c = 0; c < 16; c++) dv[c] = (_Float16)0.f;
        }
        const float4* sa = (const float4*)(Wa + (size_t)r * DIM + i0);
        const float4* sg = (const float4*)(Wg + (size_t)r * DIM + i0);
        _Float16* da = &wah[r * LDH + i0];
        _Float16* dg = &wgh[r * LDH + i0];
#pragma unroll
        for (int c = 0; c < 4; c++) {
            float4 qa = sa[c], qg = sg[c];
            da[4*c+0] = (_Float16)qa.x; da[4*c+1] = (_Float16)qa.y;
            da[4*c+2] = (_Float16)qa.z; da[4*c+3] = (_Float16)qa.w;
            dg[4*c+0] = (_Float16)qg.x; dg[4*c+1] = (_Float16)qg.y;
            dg[4*c+2] = (_Float16)qg.z; dg[4*c+3] = (_Float16)qg.w;
        }
        if (tid < 64)       bx[0 * LDH + tid] = (_Float16)gl[tid];
        else if (tid < 128) bx[1 * LDH + (tid - 64)] = (_Float16)gr[tid - 64];
        for (int x = tid; x < 12 * 64; x += 256)
            bx[(4 + (x >> 6)) * LDH + (x & 63)] = (_Float16)0.f;
    }
    __syncthreads();
    if (tid < 64) {
        int i = tid;
        float acc = 0.f;
        for (int k = 0; k < 64; k++) acc = fmaf(a_l[k], (float)wah[k * LDH + i], acc);
        bx[2 * LDH + i] = (_Float16)acc;
    } else if (tid < 128) {
        int i = tid - 64;
        float acc = 0.f;
        for (int k = 0; k < 64; k++) acc = fmaf(a_r[k], (float)wah[k * LDH + i], acc);
        bx[3 * LDH + i] = (_Float16)acc;
    }
    __syncthreads();

    int lane = tid & 63;
    int m0 = (tid >> 6) * 16;
    int rb = lane & 15;
    int q  = lane >> 4;

    half8 a_lo = *(const half8*)&vt[(m0 + rb) * LDH + q * 8];
    half8 a_hi = *(const half8*)&vt[(m0 + rb) * LDH + 32 + q * 8];

    float4v zacc[4], uacc[4], sacc;
#pragma unroll
    for (int tc = 0; tc < 4; tc++) { zacc[tc] = (float4v)0.f; uacc[tc] = (float4v)0.f; }
    sacc = (float4v)0.f;

#pragma unroll
    for (int tc = 0; tc < 4; tc++) {
        int c0 = tc * 16;
        half8 blo = *(const half8*)&wah[(c0 + rb) * LDH + q * 8];
        half8 bhi = *(const half8*)&wah[(c0 + rb) * LDH + 32 + q * 8];
        zacc[tc] = __builtin_amdgcn_mfma_f32_16x16x32_f16(a_lo, blo, zacc[tc], 0, 0, 0);
        zacc[tc] = __builtin_amdgcn_mfma_f32_16x16x32_f16(a_hi, bhi, zacc[tc], 0, 0, 0);
        half8 glo = *(const half8*)&wgh[(c0 + rb) * LDH + q * 8];
        half8 ghi = *(const half8*)&wgh[(c0 + rb) * LDH + 32 + q * 8];
        uacc[tc] = __builtin_amdgcn_mfma_f32_16x16x32_f16(a_lo, glo, uacc[tc], 0, 0, 0);
        uacc[tc] = __builtin_amdgcn_mfma_f32_16x16x32_f16(a_hi, ghi, uacc[tc], 0, 0, 0);
    }
    {
        half8 blo = *(const half8*)&bx[rb * LDH + q * 8];
        half8 bhi = *(const half8*)&bx[rb * LDH + 32 + q * 8];
        sacc = __builtin_amdgcn_mfma_f32_16x16x32_f16(a_lo, blo, sacc, 0, 0, 0);
        sacc = __builtin_amdgcn_mfma_f32_16x16x32_f16(a_hi, bhi, sacc, 0, 0, 0);
    }

#pragma unroll
    for (int r = 0; r < 4; r++) {
        int n = base + m0 + q * 4 + r;
        if (n < N) {
#pragma unroll
            for (int tc = 0; tc < 4; tc++)
                zu[(size_t)n * DIM + tc * 16 + rb] = __floats2half2_rn(zacc[tc][r], uacc[tc][r]);
        }
    }
    // scalars: col rb of sacc = {g0, t_gr, s_l, s_r} for rb=0..3
    if (rb < 4) {
#pragma unroll
        for (int r = 0; r < 4; r++) {
            int n = base + m0 + q * 4 + r;
            if (n < N) {
                float val = sacc[r];
                if (rb == 0) g0[n] = val;
                else if (rb == 1) st[n].y = val;   // t_gr
                else if (rb == 2) st[n].x = val;   // s_l
                else s_r[n] = val;
            }
        }
    }
}

// ---------------------------------------------------------------------------
// Phase 2: one block per bucket. In-block scan of final bucket counts ->
// compact CSR base; LDS hist of dst&255 -> per-node offs/deg; placement
// into the block-owned ~16KB sp_s window.
// ---------------------------------------------------------------------------
__global__ __launch_bounds__(256) void bucket_to_csr(
    const uint2* __restrict__ tmp, const int* __restrict__ bcur0,
    int* __restrict__ offs, int* __restrict__ deg,
    unsigned int* __restrict__ sp_s, int N)
{
    __shared__ int h[256], excl[256], cur[256], sc[256];
    int b = blockIdx.x;
    int t = threadIdx.x;
    int c = bcur0[t]; if (c > CAP) c = CAP;
    sc[t] = c;
    __syncthreads();
    for (int off = 1; off < 256; off <<= 1) {
        int y = (t >= off) ? sc[t - off] : 0;
        __syncthreads();
        sc[t] += y;
        __syncthreads();
    }
    int start = (b == 0) ? 0 : sc[b - 1];
    int bcnt = sc[b] - start;
    const uint2* reg = tmp + (size_t)b * CAP;
    h[t] = 0; cur[t] = 0;
    __syncthreads();
    for (int i = t; i < bcnt; i += 256)
        atomicAdd(&h[reg[i].y & 255], 1);
    __syncthreads();
    int x = h[t];
    excl[t] = x;
    __syncthreads();
    for (int off = 1; off < 256; off <<= 1) {
        int y = (t >= off) ? excl[t - off] : 0;
        __syncthreads();
        excl[t] += y;
        __syncthreads();
    }
    int ex = excl[t] - x;
    int n = (b << 8) + t;
    if (n < N) { offs[n] = start + ex; deg[n] = x; }
    __syncthreads();
    excl[t] = ex;
    __syncthreads();
    for (int i = t; i < bcnt; i += 256) {
        uint2 r = reg[i];
        int d8 = r.y & 255;
        int pos = start + excl[d8] + atomicAdd(&cur[d8], 1);
        sp_s[pos] = r.x;
    }
}

// ---------------------------------------------------------------------------
// Aggregate with fused flash-style softmax. One wave per dst node.
// Phase A: lane j computes ea_j + msum (st = {s_l,t_gr} single 8B gather);
// Phase B: per-edge {rec,w} shfl broadcast, lane=feature zu gather.
// ---------------------------------------------------------------------------
__global__ __launch_bounds__(256) void aggregate(
    const int* __restrict__ offs, const int* __restrict__ deg_a,
    const unsigned int* __restrict__ sp_s,
    const __half2* __restrict__ zu,
    const float2* __restrict__ st, const float* __restrict__ s_r,
    const float* __restrict__ g0, const float* __restrict__ gm,
    float* __restrict__ out, int N)
{
    int n = __builtin_amdgcn_readfirstlane((blockIdx.x * 256 + threadIdx.x) >> 6);
    int k = threadIdx.x & 63;
    if (n >= N) return;
    int deg = deg_a[n];
    size_t outIdx = (size_t)n * DIM + k;
    if (deg == 0) { out[outIdx] = 0.f; return; }
    int start = offs[n];
    float srn = s_r[n];

    float m = -INFINITY, denom = 0.f, hk = 0.f, mfk = -INFINITY, msum = 0.f;
    for (int c0 = 0; c0 < deg; c0 += 64) {
        int cn = deg - c0; if (cn > 64) cn = 64;
        unsigned rec = 0;
        float ea = -INFINITY;
        if (k < cn) {
            rec = sp_s[start + c0 + k];            // coalesced 256B load
            float2 stv = st[rec >> 16];            // one 8B gather: {s_l, t_gr}
            float pw = __half2float(__ushort_as_half((unsigned short)(rec & 0xffffu)));
            ea = fmaf(pw, stv.x, srn);
            ea = ea > 0.f ? ea : SLOPE * ea;       // leaky_relu
            msum = fmaf(pw, stv.y, msum);
        }
        float mc = ea;
#pragma unroll
        for (int off = 32; off; off >>= 1) mc = fmaxf(mc, __shfl_xor(mc, off, 64));
        float mnew = fmaxf(m, mc);
        float scale = __expf(m - mnew);            // 0 on first chunk
        float w = __expf(ea - mnew);               // 0 for lanes >= cn
        float sw = w;
#pragma unroll
        for (int off = 32; off; off >>= 1) sw += __shfl_xor(sw, off, 64);
        denom = denom * scale + sw;
        hk *= scale;
        m = mnew;
        int j = 0;
        for (; j + 8 <= cn; j += 8) {
            unsigned r8[8]; float w8[8]; __half2 q8[8];
#pragma unroll
            for (int i = 0; i < 8; i++) {
                r8[i] = __shfl(rec, j + i, 64);
                w8[i] = __shfl(w, j + i, 64);
            }
#pragma unroll
            for (int i = 0; i < 8; i++) q8[i] = zu[(size_t)(r8[i] >> 16) * DIM + k];
#pragma unroll
            for (int i = 0; i < 8; i++) {
                float2 f = __half22float2(q8[i]);
                float pwj = __half2float(__ushort_as_half((unsigned short)(r8[i] & 0xffffu)));
                hk = fmaf(w8[i], f.x, hk);
                mfk = fmaxf(mfk, pwj * f.y);
            }
        }
        for (; j < cn; j++) {
            unsigned rj = __shfl(rec, j, 64);
            float wj = __shfl(w, j, 64);
            __half2 q = zu[(size_t)(rj >> 16) * DIM + k];
            float2 f = __half22float2(q);
            float pwj = __half2float(__ushort_as_half((unsigned short)(rj & 0xffffu)));
            hk = fmaf(wj, f.x, hk);
            mfk = fmaxf(mfk, pwj * f.y);
        }
    }
#pragma unroll
    for (int off = 32; off; off >>= 1) msum += __shfl_xor(msum, off, 64);
    float r = gm[k] * mfk;
#pragma unroll
    for (int off = 32; off; off >>= 1) r += __shfl_down(r, off, 64);
    r = __shfl(r, 0, 64);
    float meanDot = msum / (float)deg;
    float xg = g0[n] + r + meanDot;
    float gate = 1.f / (1.f + __expf(-xg));
    out[outIdx] = gate * hk / fmaxf(denom, 1e-16f);
}

// ---------------------------------------------------------------------------
extern "C" void kernel_launch(void* const* d_in, const int* in_sizes, int n_in,
                              void* d_out, int out_size, void* d_ws, size_t ws_size,
                              hipStream_t stream)
{
    const float* v     = (const float*)d_in[0];
    const float* pre_w = (const float*)d_in[1];
    const int*   src   = (const int*)d_in[2];
    const int*   dst   = (const int*)d_in[3];
    const float* Wa    = (const float*)d_in[4];
    const float* a_l   = (const float*)d_in[5];
    const float* a_r   = (const float*)d_in[6];
    const float* Wg    = (const float*)d_in[7];
    const float* gl    = (const float*)d_in[8];
    const float* gm    = (const float*)d_in[9];
    const float* gr    = (const float*)d_in[10];
    int N = in_sizes[0] / DIM;
    int E = in_sizes[2];
    int nbuck = (N + 255) >> 8;
    int scBlocks = (E + P1_CHUNK - 1) / P1_CHUNK;
    int npBlocks = (N + 63) / 64;

    // workspace layout (~30 MB)
    char* ws    = (char*)d_ws;
    __half2* zu = (__half2*)ws;                       // N*DIM*4B = 12.8MB
    float2* st  = (float2*)(ws + (size_t)N * DIM * 4);// N*8B
    float* s_r  = (float*)(st + N);
    float* g0   = s_r + N;
    int* offs   = (int*)(g0 + N);
    int* deg    = offs + N;
    int* bcur0  = deg + N;                            // 256 (zeroed)
    uint2* tmp  = (uint2*)(bcur0 + 256);              // nbuck*CAP*8B
    unsigned int* sp_s = (unsigned int*)(tmp + (size_t)nbuck * CAP);  // E*4B

    hipMemsetAsync(bcur0, 0, 256 * sizeof(int), stream);

    proj_scatter<<<scBlocks + npBlocks, 256, 0, stream>>>(
        v, Wa, Wg, a_l, a_r, gl, gr, zu, st, s_r, g0,
        src, dst, pre_w, bcur0, tmp, N, E, scBlocks);

    bucket_to_csr<<<nbuck, 256, 0, stream>>>(
        tmp, bcur0, offs, deg, sp_s, N);

    aggregate<<<(N + 3) / 4, 256, 0, stream>>>(
        offs, deg, sp_s, zu, st, s_r, g0, gm, (float*)d_out, N);
}